// Round 9
// baseline (1632.080 us; speedup 1.0000x reference)
//
#include <hip/hip_runtime.h>
#include <math.h>

// ---------------------------------------------------------------------------
// OmniFluids2D forward on MI355X. bf16 dataflow + MFMA everywhere GEMM-shaped.
// Y/X spectral branches merged into double-width launches. B=4, 256^2, W=64.
// R8/R9: diagnostic round (R9 = R8 resubmit after GPU-acquisition timeout).
//     k_headm split into 4 px-quarter dispatches (~65us each, zero math
//     change) so the layer kernels (wtf/mixm2/ti2/ffm, the ~1280us that
//     top-5 has never shown) surface with full counters.
// ---------------------------------------------------------------------------

typedef __attribute__((ext_vector_type(8))) short sh8;
typedef __attribute__((ext_vector_type(4))) float f4;

__device__ __forceinline__ float fast_rcp(float x) {
#if defined(__has_builtin)
#if __has_builtin(__builtin_amdgcn_rcpf)
    return __builtin_amdgcn_rcpf(x);
#else
    return 1.0f / x;
#endif
#else
    return 1.0f / x;
#endif
}

__device__ __forceinline__ float gelu_f(float v) {          // exact (att only)
    return 0.5f * v * (1.0f + erff(v * 0.70710678118654752f));
}
__device__ __forceinline__ float gelu_fast(float v) {       // tanh-approx, rcp
    float s = v * (1.5957691216f + 0.0713548162f * v * v);
    float e = __expf(-s);
    return v * fast_rcp(1.0f + e);
}
__device__ __forceinline__ unsigned short f2bf(float x) {
    unsigned int u = __float_as_uint(x);
    u += 0x7fffu + ((u >> 16) & 1u);
    return (unsigned short)(u >> 16);
}
__device__ __forceinline__ float bf2f(unsigned short h) {
    return __uint_as_float(((unsigned int)h) << 16);
}

// --------------- fused front: prep (tables/weights) + att + embed ------------
__global__ __launch_bounds__(256) void k_front(
    const float* __restrict__ ff_w0, const float* __restrict__ ff_w1,
    const float* __restrict__ fa_w, const float* __restrict__ fb_w,
    const float* __restrict__ fa_b, const float* __restrict__ fb_b,
    const float* __restrict__ c1w, const float* __restrict__ c2w,
    unsigned short* __restrict__ tabBf,
    unsigned short* __restrict__ W0T, unsigned short* __restrict__ W1T,
    unsigned short* __restrict__ Wcat, float* __restrict__ bcat,
    unsigned int* __restrict__ c1p, unsigned int* __restrict__ c2p,
    const float* __restrict__ params,
    const float* __restrict__ w1, const float* __restrict__ b1,
    const float* __restrict__ w2, const float* __restrict__ b2,
    const float* __restrict__ w3, const float* __restrict__ b3,
    float* __restrict__ att,
    const float* __restrict__ xin,
    const float* __restrict__ inw, const float* __restrict__ inb,
    unsigned short* __restrict__ Hb)
{
    int bid = blockIdx.x;
    int tid = threadIdx.x;
    if (bid == 0) {
        // ---- routing attention, all layers, 128 active threads ----
        __shared__ float A1[128], A2[128], LG[4];
        int j = tid;
        for (int lay = 0; lay < 4; ++lay) {
            for (int b = 0; b < 4; ++b) {
                if (j < 128) {
                    float s = b1[lay * 128 + j];
                    for (int p = 0; p < 8; ++p)
                        s += params[b * 8 + p] * w1[(lay * 8 + p) * 128 + j];
                    A1[j] = gelu_f(s);
                }
                __syncthreads();
                if (j < 128) {
                    float s = b2[lay * 128 + j];
                    for (int q = 0; q < 128; ++q) s += A1[q] * w2[(lay * 128 + q) * 128 + j];
                    A2[j] = gelu_f(s);
                }
                __syncthreads();
                if (j < 4) {
                    float tacc = b3[lay * 4 + j];
                    for (int q = 0; q < 128; ++q) tacc += A2[q] * w3[(lay * 128 + q) * 4 + j];
                    LG[j] = tacc * 0.1f;
                }
                __syncthreads();
                if (j == 0) {
                    float mx = fmaxf(fmaxf(LG[0], LG[1]), fmaxf(LG[2], LG[3]));
                    float e0 = expf(LG[0] - mx), e1 = expf(LG[1] - mx);
                    float e2 = expf(LG[2] - mx), e3 = expf(LG[3] - mx);
                    float inv = 1.0f / (e0 + e1 + e2 + e3);
                    att[lay * 16 + b * 4 + 0] = e0 * inv;
                    att[lay * 16 + b * 4 + 1] = e1 * inv;
                    att[lay * 16 + b * 4 + 2] = e2 * inv;
                    att[lay * 16 + b * 4 + 3] = e3 * inv;
                }
                __syncthreads();
            }
        }
        return;
    }
    if (bid <= 1128) {
        // ---- prep: trig tables + weight packing ----
        int idx = (bid - 1) * 256 + tid;
        if (idx < 131072) {
            int t = idx >> 15, r = idx & 32767;
            const double PI = 3.14159265358979323846;
            const double s510 = 1.0 / sqrt(510.0);
            double v = 0.0;
            if (t == 0) {            // TAB_YF [row=2m+c][y]  (128x256)
                int row = r >> 8, y = r & 255;
                int m = row >> 1, c = row & 1;
                double ang = 2.0 * PI * (double)(m * y) / 256.0;
                v = (c == 0 ? cos(ang) : -sin(ang)) / 16.0;
            } else if (t == 1) {     // TAB_XF [row=2k+c][x]  (128x256)
                int row = r >> 8, xx = r & 255;
                int k = row >> 1, c = row & 1;
                if (c == 0) {
                    v = 0.0;
                    if (xx == 0)   v = s510;
                    if (xx == 255) v = (k & 1) ? -s510 : s510;
                } else {
                    double ang = PI * (double)(k * xx) / 255.0;
                    v = -2.0 * s510 * sin(ang);
                }
            } else if (t == 2) {     // TAB_YI [y][row=2m+c]  (256x128)
                int y = r >> 7, row = r & 127;
                int m = row >> 1, c = row & 1;
                double ang = 2.0 * PI * (double)(m * y) / 256.0;
                if (c == 0) v = (m == 0 ? 1.0 : 2.0 * cos(ang)) / 16.0;
                else        v = (m == 0 ? 0.0 : -2.0 * sin(ang) / 16.0);
            } else {                 // TAB_XI [x][row=2k+c]  (256x128)
                int xx = r >> 7, row = r & 127;
                int k = row >> 1, c = row & 1;
                double ang = PI * (double)(k * xx) / 255.0;
                if (c == 0) v = s510 * (k == 0 ? 1.0 : 2.0 * cos(ang));
                else        v = (k == 0 ? 0.0 : -2.0 * s510 * sin(ang));
            }
            tabBf[idx] = f2bf((float)v);
            return;
        }
        idx -= 131072;
        if (idx < 65536) {
            int l = idx >> 14, rem = idx & 16383;
            int n = rem >> 6, k = rem & 63;
            W0T[idx] = f2bf(ff_w0[l * 16384 + k * 256 + n]);
        } else if (idx < 131072) {
            int j = idx - 65536;
            int l = j >> 14, rem = j & 16383;
            int n = rem >> 8, k = rem & 255;
            W1T[j] = f2bf(ff_w1[l * 16384 + k * 64 + n]);
        } else if (idx < 156672) {
            int j = idx - 131072;
            int f = j / 5120, r2 = j % 5120;
            int n = r2 >> 6, k = r2 & 63;
            float v = 0.0f;
            if (n < 36)      v = fa_w[f * 2304 + k * 36 + n];
            else if (n < 70) v = fb_w[f * 2176 + k * 34 + (n - 36)];
            Wcat[j] = f2bf(v);
        } else if (idx < 157072) {
            int j = idx - 156672;
            int f = j / 80, n = j % 80;
            float v = 0.0f;
            if (n < 36)      v = fa_b[f * 36 + n];
            else if (n < 70) v = fb_b[f * 34 + (n - 36)];
            bcat[j] = v;
        } else if (idx < 157552) {
            int j = idx - 157072;         // 0..479 (workspace layout compat)
            int half = j >= 240;
            int r = j - half * 240;
            int fc = r / 6, jj = r % 6;
            const float* src = half ? c2w : c1w;
            unsigned int u = (unsigned int)f2bf(src[fc * 12 + 2 * jj])
                           | ((unsigned int)f2bf(src[fc * 12 + 2 * jj + 1]) << 16);
            (half ? c2p : c1p)[r] = u;
        }
        return;
    }
    // ---- input embedding ----
    {
        long gid = (long)(bid - 1129) * 256 + tid;   // 0..4194303
        long px = gid >> 4;
        int c4 = (int)(gid & 15) * 4;
        int y = (int)(px & 255), xi = (int)((px >> 8) & 255);
        const float* xp = xin + px * 5;
        float v[7];
        v[0] = xp[0]; v[1] = xp[1]; v[2] = xp[2]; v[3] = xp[3]; v[4] = xp[4];
        const float STEP = 6.283185307179586f / 256.0f;
        v[5] = xi * STEP;
        v[6] = y * STEP;
        float r[4];
        #pragma unroll
        for (int c = 0; c < 4; ++c) {
            int ch = c4 + c;
            float s = inb[ch];
            #pragma unroll
            for (int p = 0; p < 7; ++p) s += v[p] * inw[p * 64 + ch];
            r[c] = gelu_fast(s);
        }
        uint2 uu;
        uu.x = (unsigned int)f2bf(r[0]) | ((unsigned int)f2bf(r[1]) << 16);
        uu.y = (unsigned int)f2bf(r[2]) | ((unsigned int)f2bf(r[3]) << 16);
        *(uint2*)(Hb + px * 64 + c4) = uu;
    }
}

// ------------------------- B^T staging: global rows -> lds[n][k] -------------
__device__ __forceinline__ void stage_bt(unsigned short* lds, int pitch,
    const unsigned short* src, int rowStride, int K, int tid)
{
    int pairs = K >> 1;
    int tasks = pairs * 8;
    for (int idx = tid; idx < tasks; idx += 256) {
        int p = idx & (pairs - 1);
        int cg = idx / pairs;
        const unsigned short* s0 = src + (long)(2 * p) * rowStride + cg * 8;
        sh8 r0 = *(const sh8*)s0;
        sh8 r1 = *(const sh8*)(s0 + rowStride);
        unsigned short* dbase = lds + cg * 8 * pitch + 2 * p;
        #pragma unroll
        for (int j = 0; j < 8; ++j) {
            unsigned int u = (unsigned int)(unsigned short)r0[j]
                           | ((unsigned int)(unsigned short)r1[j] << 16);
            *(unsigned int*)(dbase + j * pitch) = u;
        }
    }
}

// --------------- fused W-generation + forward transform ----------------------
// bid < 512: wfuse half. bid >= 512: tf2 half -> Z in [b][r][s][o] layout.
__global__ __launch_bounds__(256) void k_wtf(
    const float* __restrict__ fwY, const float* __restrict__ fwX,
    const float* __restrict__ att,
    unsigned short* __restrict__ WrTy, unsigned short* __restrict__ WiTy,
    unsigned short* __restrict__ WinTy,
    unsigned short* __restrict__ WrTx, unsigned short* __restrict__ WiTx,
    unsigned short* __restrict__ WinTx,
    const unsigned short* __restrict__ tabY, const unsigned short* __restrict__ tabX,
    const unsigned short* __restrict__ Hb,
    unsigned short* __restrict__ Zy, unsigned short* __restrict__ Zx)
{
    __shared__ __align__(16) unsigned char smem[34816];  // max(tf2 34816, wfuse 33280)
    int bid = blockIdx.x;
    int tid = threadIdx.x;
    if (bid < 512) {
        // ---- wfuse ----
        int o = bid & 63, b = (bid >> 6) & 3, z = bid >> 8;
        const float* fw = z ? fwX : fwY;
        unsigned short* WrT  = z ? WrTx  : WrTy;
        unsigned short* WiT  = z ? WiTx  : WiTy;
        unsigned short* WinT = z ? WinTx : WinTy;
        float av[4];
        av[0] = att[b * 4 + 0]; av[1] = att[b * 4 + 1];
        av[2] = att[b * 4 + 2]; av[3] = att[b * 4 + 3];
        float acc[32];
        #pragma unroll
        for (int j = 0; j < 32; ++j) acc[j] = 0.0f;
        long toff = (long)(tid >> 7) * 8192 + o * 128 + (tid & 127);
        for (int k = 0; k < 4; ++k) {
            const float* p = fw + (long)k * 524288 + toff;
            float a = av[k];
            #pragma unroll
            for (int j = 0; j < 32; ++j) acc[j] += a * p[j * 16384];
        }
        float* ldsR = (float*)smem;              // 64*65*4 = 16640 B
        float* ldsI = (float*)(smem + 16640);    // +16640 = 33280 B total
        int m = (tid & 127) >> 1, c = tid & 1;
        int ib = tid >> 7;
        #pragma unroll
        for (int j = 0; j < 32; ++j) {
            int i = j * 2 + ib;
            (c ? ldsI : ldsR)[m * 65 + i] = acc[j];
        }
        __syncthreads();
        long ob = (long)b * 262144 + o * 64;   // + m*4096 + i
        #pragma unroll
        for (int it = 0; it < 16; ++it) {
            int idx = it * 256 + tid;
            int mm = idx >> 6, ii = idx & 63;
            float rr = ldsR[mm * 65 + ii], im = ldsI[mm * 65 + ii];
            long a = ob + (long)mm * 4096 + ii;
            WrT[a]  = f2bf(rr);
            WiT[a]  = f2bf(im);
            WinT[a] = f2bf(-im);
        }
        return;
    }
    // ---- tf2 ----
    unsigned short* ldsB = (unsigned short*)smem;   // 64*272*2 = 34816 B
    int g2 = bid - 512;
    int br = g2 >> 10, g = g2 & 1023;
    int b = g >> 8, s = g & 255;
    const unsigned short* tab = br ? tabX : tabY;
    unsigned short* Zo = br ? Zx : Zy;
    long sLo = br ? 64L : 16384L;
    int rowStride = br ? 16384 : 64;
    const unsigned short* src = Hb + (long)b * 4194304 + (long)s * sLo;
    stage_bt(ldsB, 272, src, rowStride, 256, tid);
    __syncthreads();
    int w = tid >> 6, lane = tid & 63, q = lane >> 4, ln = lane & 15;
    f4 acc[2][4];
    #pragma unroll
    for (int mi = 0; mi < 2; ++mi)
        #pragma unroll
        for (int ni = 0; ni < 4; ++ni) acc[mi][ni] = (f4){0.f, 0.f, 0.f, 0.f};
    for (int kc = 0; kc < 256; kc += 32) {
        sh8 a[2], bf[4];
        #pragma unroll
        for (int mi = 0; mi < 2; ++mi)
            a[mi] = *(const sh8*)(tab + (w * 32 + mi * 16 + ln) * 256 + kc + q * 8);
        #pragma unroll
        for (int ni = 0; ni < 4; ++ni)
            bf[ni] = *(const sh8*)(ldsB + (ni * 16 + ln) * 272 + kc + q * 8);
        #pragma unroll
        for (int mi = 0; mi < 2; ++mi)
            #pragma unroll
            for (int ni = 0; ni < 4; ++ni)
                acc[mi][ni] = __builtin_amdgcn_mfma_f32_16x16x32_bf16(
                    a[mi], bf[ni], acc[mi][ni], 0, 0, 0);
    }
    // write Z[b][r][s][o]
    long zB = (long)b * 2097152 + (long)s * 64;
    #pragma unroll
    for (int mi = 0; mi < 2; ++mi)
        #pragma unroll
        for (int ni = 0; ni < 4; ++ni)
            #pragma unroll
            for (int reg = 0; reg < 4; ++reg) {
                int r = w * 32 + mi * 16 + q * 4 + reg;
                Zo[zB + (long)r * 16384 + ni * 16 + ln] = f2bf(acc[mi][ni][reg]);
            }
}

// ------------------------- MFMA complex mode-mix, both branches --------------
// Z layout [b][r][s][o]: freq rows 2m (Re) / 2m+1 (Im) are 16384-sh planes;
// lane stride along s is 64 sh (128 B) -> fully-coalesced reads and writes.
__global__ __launch_bounds__(256) void k_mixm2(
    unsigned short* Zy, unsigned short* Zx,
    const unsigned short* __restrict__ WrTy, const unsigned short* __restrict__ WiTy,
    const unsigned short* __restrict__ WinTy,
    const unsigned short* __restrict__ WrTx, const unsigned short* __restrict__ WiTx,
    const unsigned short* __restrict__ WinTx)
{
    int xt = blockIdx.x, g = blockIdx.y, z = blockIdx.z;
    unsigned short* Z = z ? Zx : Zy;
    const unsigned short* WrT  = z ? WrTx  : WrTy;
    const unsigned short* WiT  = z ? WiTx  : WiTy;
    const unsigned short* WinT = z ? WinTx : WinTy;
    int b = g >> 6, m = g & 63;
    int tid = threadIdx.x, w = tid >> 6, lane = tid & 63, q = lane >> 4, ln = lane & 15;
    long zBr = (long)b * 2097152 + (long)(2 * m) * 16384;   // Re plane; Im at +16384
    long wB = (long)b * 262144 + (long)m * 4096;
    int s0 = xt * 64 + w * 16;
    f4 aR[4], aI[4];
    #pragma unroll
    for (int nt = 0; nt < 4; ++nt) { aR[nt] = (f4){0.f,0.f,0.f,0.f}; aI[nt] = (f4){0.f,0.f,0.f,0.f}; }
    for (int kc = 0; kc < 64; kc += 32) {
        sh8 zr = *(const sh8*)(Z + zBr + (long)(s0 + ln) * 64 + kc + q * 8);
        sh8 zi = *(const sh8*)(Z + zBr + 16384 + (long)(s0 + ln) * 64 + kc + q * 8);
        #pragma unroll
        for (int nt = 0; nt < 4; ++nt) {
            int o = nt * 16 + ln;
            sh8 wr = *(const sh8*)(WrT + wB + o * 64 + kc + q * 8);
            sh8 wi = *(const sh8*)(WiT + wB + o * 64 + kc + q * 8);
            sh8 wn = *(const sh8*)(WinT + wB + o * 64 + kc + q * 8);
            aR[nt] = __builtin_amdgcn_mfma_f32_16x16x32_bf16(zr, wr, aR[nt], 0, 0, 0);
            aR[nt] = __builtin_amdgcn_mfma_f32_16x16x32_bf16(zi, wn, aR[nt], 0, 0, 0);
            aI[nt] = __builtin_amdgcn_mfma_f32_16x16x32_bf16(zr, wi, aI[nt], 0, 0, 0);
            aI[nt] = __builtin_amdgcn_mfma_f32_16x16x32_bf16(zi, wr, aI[nt], 0, 0, 0);
        }
    }
    #pragma unroll
    for (int nt = 0; nt < 4; ++nt)
        #pragma unroll
        for (int reg = 0; reg < 4; ++reg) {
            int s = s0 + q * 4 + reg;
            long a = zBr + (long)s * 64 + nt * 16 + ln;
            Z[a]          = f2bf(aR[nt][reg]);
            Z[a + 16384]  = f2bf(aI[nt][reg]);
        }
}

// ------------------------- MFMA inverse transform, both branches -------------
// Z layout [b][r][s][o]: stage with rowStride 16384 at base +s*64.
// z=0: Ry[b][x][y][o] from Zy ; z=1: Rx[b][y][x][o] from Zx (both contiguous).
__global__ __launch_bounds__(256) void k_ti2(
    const unsigned short* __restrict__ tabY, const unsigned short* __restrict__ tabX,
    const unsigned short* __restrict__ Zy, const unsigned short* __restrict__ Zx,
    unsigned short* __restrict__ Ry, unsigned short* __restrict__ Rx)
{
    __shared__ __align__(16) unsigned short ldsB[64 * 144];
    int g = blockIdx.x, br = blockIdx.y;
    int b = g >> 8, s = g & 255;
    const unsigned short* tab = br ? tabX : tabY;
    const unsigned short* Zl  = br ? Zx : Zy;
    unsigned short* Ro = br ? Rx : Ry;
    int tid = threadIdx.x;
    const unsigned short* src = Zl + (long)b * 2097152 + (long)s * 64;
    stage_bt(ldsB, 144, src, 16384, 128, tid);
    __syncthreads();
    int w = tid >> 6, lane = tid & 63, q = lane >> 4, ln = lane & 15;
    f4 acc[4][4];
    #pragma unroll
    for (int mi = 0; mi < 4; ++mi)
        #pragma unroll
        for (int ni = 0; ni < 4; ++ni) acc[mi][ni] = (f4){0.f, 0.f, 0.f, 0.f};
    for (int kc = 0; kc < 128; kc += 32) {
        sh8 a[4], bf[4];
        #pragma unroll
        for (int mi = 0; mi < 4; ++mi)
            a[mi] = *(const sh8*)(tab + (w * 64 + mi * 16 + ln) * 128 + kc + q * 8);
        #pragma unroll
        for (int ni = 0; ni < 4; ++ni)
            bf[ni] = *(const sh8*)(ldsB + (ni * 16 + ln) * 144 + kc + q * 8);
        #pragma unroll
        for (int mi = 0; mi < 4; ++mi)
            #pragma unroll
            for (int ni = 0; ni < 4; ++ni)
                acc[mi][ni] = __builtin_amdgcn_mfma_f32_16x16x32_bf16(
                    a[mi], bf[ni], acc[mi][ni], 0, 0, 0);
    }
    long rB = (long)b * 4194304 + (long)s * 16384;
    #pragma unroll
    for (int mi = 0; mi < 4; ++mi)
        #pragma unroll
        for (int ni = 0; ni < 4; ++ni)
            #pragma unroll
            for (int reg = 0; reg < 4; ++reg) {
                int r2 = w * 64 + mi * 16 + q * 4 + reg;
                Ro[rB + (long)r2 * 64 + ni * 16 + ln] = f2bf(acc[mi][ni][reg]);
            }
}

// ------------------------- MFMA fused FeedForward + LN -----------------------
// A = bf16(Ry + Rx) built in registers; residual stream in bf16 (Hb).
__global__ __launch_bounds__(256) void k_ffm(
    const unsigned short* __restrict__ Ry, const unsigned short* __restrict__ Rx,
    const unsigned short* __restrict__ W0T, const float* __restrict__ b0,
    const unsigned short* __restrict__ W1T, const float* __restrict__ b1,
    const float* __restrict__ g1, const float* __restrict__ be1,
    unsigned short* __restrict__ Hb, int last)
{
    __shared__ __align__(16) unsigned short T[64 * 264];
    int m0 = blockIdx.x * 64;
    int tid = threadIdx.x, w = tid >> 6, lane = tid & 63, q = lane >> 4, ln = lane & 15;
    int row = m0 + w * 16 + ln;
    int bb = row >> 16, xx2 = (row >> 8) & 255, yy = row & 255;
    const unsigned short* ryp = Ry + (long)row * 64;
    const unsigned short* rxp = Rx + (long)bb * 4194304 + (long)yy * 16384 + xx2 * 64;
    // phase 1: T = relu((Ry+Rx) @ W0 + b0), rows w*16..+15, N=256
    {
        f4 acc1[16];
        #pragma unroll
        for (int nt = 0; nt < 16; ++nt) acc1[nt] = (f4){0.f, 0.f, 0.f, 0.f};
        for (int kc = 0; kc < 64; kc += 32) {
            sh8 ry = *(const sh8*)(ryp + kc + q * 8);
            sh8 rx = *(const sh8*)(rxp + kc + q * 8);
            sh8 a;
            #pragma unroll
            for (int j = 0; j < 8; ++j)
                a[j] = (short)f2bf(bf2f((unsigned short)ry[j]) + bf2f((unsigned short)rx[j]));
            #pragma unroll
            for (int nt = 0; nt < 16; ++nt) {
                sh8 bf = *(const sh8*)(W0T + (nt * 16 + ln) * 64 + kc + q * 8);
                acc1[nt] = __builtin_amdgcn_mfma_f32_16x16x32_bf16(a, bf, acc1[nt], 0, 0, 0);
            }
        }
        #pragma unroll
        for (int nt = 0; nt < 16; ++nt) {
            int n = nt * 16 + ln;
            float bias = b0[n];
            #pragma unroll
            for (int reg = 0; reg < 4; ++reg) {
                int m = w * 16 + q * 4 + reg;
                T[m * 264 + n] = f2bf(fmaxf(acc1[nt][reg] + bias, 0.0f));
            }
        }
    }
    // phase 2 (intra-wave LDS dep): t = T @ W1 + b1, then LN + residual
    f4 acc2[4];
    #pragma unroll
    for (int nt = 0; nt < 4; ++nt) acc2[nt] = (f4){0.f, 0.f, 0.f, 0.f};
    for (int kc = 0; kc < 256; kc += 32) {
        sh8 a = *(const sh8*)(T + (w * 16 + ln) * 264 + kc + q * 8);
        #pragma unroll
        for (int nt = 0; nt < 4; ++nt) {
            sh8 bf = *(const sh8*)(W1T + (nt * 16 + ln) * 256 + kc + q * 8);
            acc2[nt] = __builtin_amdgcn_mfma_f32_16x16x32_bf16(a, bf, acc2[nt], 0, 0, 0);
        }
    }
    float bia[4], gg[4], bb4[4];
    #pragma unroll
    for (int nt = 0; nt < 4; ++nt) {
        int n = nt * 16 + ln;
        bia[nt] = b1[n]; gg[nt] = g1[n]; bb4[nt] = be1[n];
    }
    #pragma unroll
    for (int reg = 0; reg < 4; ++reg) {
        float t[4];
        float s = 0.f, qs = 0.f;
        #pragma unroll
        for (int nt = 0; nt < 4; ++nt) {
            t[nt] = acc2[nt][reg] + bia[nt];
            s += t[nt]; qs += t[nt] * t[nt];
        }
        #pragma unroll
        for (int d = 1; d < 16; d <<= 1) {
            s  += __shfl_xor(s, d, 64);
            qs += __shfl_xor(qs, d, 64);
        }
        float mean = s * (1.0f / 64.0f);
        float var  = qs * (1.0f / 64.0f) - mean * mean;
        float inv  = rsqrtf(var + 1e-5f);
        int m = w * 16 + q * 4 + reg;
        long base = (long)(m0 + m) * 64;
        #pragma unroll
        for (int nt = 0; nt < 4; ++nt) {
            int n = nt * 16 + ln;
            float v = (t[nt] - mean) * inv * gg[nt] + bb4[nt];
            float hv;
            if (last) hv = gelu_fast(v);
            else      hv = bf2f(Hb[base + n]) + v;
            Hb[base + n] = f2bf(hv);
        }
    }
}

// ------------------------- output heads (MFMA ha + fp32 conv) ----------------
// px-quarter per dispatch (pxQ): dim3(256,5) x 4 launches. Same math as R4.
__global__ __launch_bounds__(256) void k_headm(
    const unsigned short* __restrict__ Hb, const float* __restrict__ x0,
    const unsigned short* __restrict__ Wcat, const float* __restrict__ bcat,
    const float* __restrict__ c1w, const float* __restrict__ c1b,
    const float* __restrict__ c2w, const float* __restrict__ c2b,
    float* __restrict__ out, int pxQ)
{
    __shared__ unsigned short ha[256 * 74];   // [px][j], pitch 74 (gcd(37,32)=1)
    int tid = threadIdx.x;
    int f = blockIdx.y;
    long px0 = (long)(pxQ * 256 + blockIdx.x) * 256;
    int w = tid >> 6, lane = tid & 63, q = lane >> 4, ln = lane & 15;

    // ha-GEMM, one mi (16 rows) at a time: acc[5] live, not acc[4][5]
    #pragma unroll
    for (int mi = 0; mi < 4; ++mi) {
        f4 acc[5];
        #pragma unroll
        for (int nt = 0; nt < 5; ++nt) acc[nt] = (f4){0.f, 0.f, 0.f, 0.f};
        #pragma unroll
        for (int kc = 0; kc < 2; ++kc) {
            sh8 a = *(const sh8*)(Hb + (px0 + w * 64 + mi * 16 + ln) * 64
                                   + kc * 32 + q * 8);
            #pragma unroll
            for (int nt = 0; nt < 5; ++nt) {
                sh8 bf = *(const sh8*)(Wcat + f * 5120 + (nt * 16 + ln) * 64
                                        + kc * 32 + q * 8);
                acc[nt] = __builtin_amdgcn_mfma_f32_16x16x32_bf16(a, bf, acc[nt], 0, 0, 0);
            }
        }
        #pragma unroll
        for (int nt = 0; nt < 5; ++nt) {
            int n = nt * 16 + ln;
            if (n < 70) {
                float bias = bcat[f * 80 + n];
                #pragma unroll
                for (int reg = 0; reg < 4; ++reg) {
                    int m = w * 64 + mi * 16 + q * 4 + reg;
                    ha[m * 74 + n] = f2bf(gelu_fast(acc[nt][reg] + bias));
                }
            }
        }
    }
    __syncthreads();

    // conv phase: one pixel per thread, fp32 FMA.
    float u2[10];
    float b2v = c2b[f];
    #pragma unroll
    for (int d = 0; d < 10; ++d) u2[d] = b2v;
    #pragma unroll
    for (int h = 0; h < 2; ++h) {
        float hw[40];   // hv[30h .. 30h+39]
        #pragma unroll
        for (int i = 0; i < 20; ++i) {
            unsigned int u = *(const unsigned int*)(ha + tid * 74 + h * 30 + 2 * i);
            hw[2 * i]     = __uint_as_float(u << 16);
            hw[2 * i + 1] = __uint_as_float(u & 0xffff0000u);
        }
        #pragma unroll 1
        for (int c = 0; c < 8; ++c) {
            int fc = f * 8 + c;
            float w1r[12], w2r[12];   // wave-uniform -> SGPRs
            #pragma unroll
            for (int j = 0; j < 12; ++j) {
                w1r[j] = c1w[fc * 12 + j];
                w2r[j] = c2w[fc * 12 + j];
            }
            float bc = c1b[fc];
            #pragma unroll
            for (int pl = 0; pl < 15; ++pl) {
                const int p = h * 15 + pl;     // compile-time after unroll
                float s = bc;
                #pragma unroll
                for (int j = 0; j < 12; ++j)
                    s = fmaf(hw[2 * pl + j], w1r[j], s);
                float g = gelu_fast(s);
                #pragma unroll
                for (int d = 0; d < 10; ++d) {
                    const int j2 = p - 2 * d;  // compile-time bounds
                    if (j2 >= 0 && j2 < 12)
                        u2[d] = fmaf(g, w2r[j2], u2[d]);
                }
            }
        }
    }
    long px = px0 + tid;
    float xv = x0[px * 5 + f];
    #pragma unroll
    for (int d = 0; d < 10; ++d)
        out[px * 50 + f * 10 + d] = xv + u2[d] * (float)(d + 1) * 0.1f;
}

// ---------------------------------------------------------------------------
extern "C" void kernel_launch(void* const* d_in, const int* in_sizes, int n_in,
                              void* d_out, int out_size, void* d_ws, size_t ws_size,
                              hipStream_t stream) {
    (void)in_sizes; (void)n_in; (void)out_size; (void)ws_size;
    const float* xin    = (const float*)d_in[0];
    const float* params = (const float*)d_in[1];
    const float* in_w   = (const float*)d_in[2];
    const float* in_b   = (const float*)d_in[3];
    const float* fnu_w1 = (const float*)d_in[4];
    const float* fnu_b1 = (const float*)d_in[5];
    const float* fnu_w2 = (const float*)d_in[6];
    const float* fnu_b2 = (const float*)d_in[7];
    const float* fnu_w3 = (const float*)d_in[8];
    const float* fnu_b3 = (const float*)d_in[9];
    const float* fw_y   = (const float*)d_in[10];
    const float* fw_x   = (const float*)d_in[11];
    const float* ff_w0  = (const float*)d_in[12];
    const float* ff_b0  = (const float*)d_in[13];
    const float* ff_w1  = (const float*)d_in[14];
    const float* ff_b1  = (const float*)d_in[15];
    const float* ln_g   = (const float*)d_in[16];
    const float* ln_b   = (const float*)d_in[17];
    const float* fa_w   = (const float*)d_in[18];
    const float* fa_b   = (const float*)d_in[19];
    const float* fb_w   = (const float*)d_in[20];
    const float* fb_b   = (const float*)d_in[21];
    const float* c1_w   = (const float*)d_in[22];
    const float* c1_b   = (const float*)d_in[23];
    const float* c2_w   = (const float*)d_in[24];
    const float* c2_b   = (const float*)d_in[25];
    float* out = (float*)d_out;
    float* ws  = (float*)d_ws;

    // workspace (float offsets), total ~41.0M floats (~164 MB)
    unsigned short* tabBf = (unsigned short*)(ws + 0);        // 131072 sh
    unsigned short* tabYF = tabBf;
    unsigned short* tabXF = tabBf + 32768;
    unsigned short* tabYI = tabBf + 65536;
    unsigned short* tabXI = tabBf + 98304;
    unsigned short* W0T   = (unsigned short*)(ws + 65536);    // 65536 sh
    unsigned short* W1T   = (unsigned short*)(ws + 98304);    // 65536 sh
    unsigned short* Wcat  = (unsigned short*)(ws + 131072);   // 25600 sh
    float* bcat = ws + 143872;                                 // 400
    float* att  = ws + 144272;                                 // 64
    unsigned int* c1p = (unsigned int*)(ws + 144336);          // 240 (layout compat)
    unsigned int* c2p = (unsigned int*)(ws + 144576);          // 240 (layout compat)
    unsigned short* Hbf = (unsigned short*)(ws + 144816);      // 16.8M sh
    // WRy..WIx fp32 slots (ws+8533424..) unused since R5 (wfuse writes bf16 direct)
    unsigned short* WrTy  = (unsigned short*)(ws + 12727728);  // 1M sh each
    unsigned short* WiTy  = (unsigned short*)(ws + 13252016);
    unsigned short* WinTy = (unsigned short*)(ws + 13776304);
    unsigned short* WrTx  = (unsigned short*)(ws + 14300592);
    unsigned short* WiTx  = (unsigned short*)(ws + 14824880);
    unsigned short* WinTx = (unsigned short*)(ws + 15349168);
    unsigned short* Zy    = (unsigned short*)(ws + 15873456);  // 8.4M sh
    unsigned short* Zx    = (unsigned short*)(ws + 20067760);  // 8.4M sh
    unsigned short* Ry    = (unsigned short*)(ws + 24262064);  // 16.8M sh
    unsigned short* Rx    = (unsigned short*)(ws + 32650672);  // 16.8M sh

    // fused front: prep + att + embed (independent) in one dispatch
    k_front<<<17513, 256, 0, stream>>>(
        ff_w0, ff_w1, fa_w, fb_w, fa_b, fb_b, c1_w, c2_w,
        tabBf, W0T, W1T, Wcat, bcat, c1p, c2p,
        params, fnu_w1, fnu_b1, fnu_w2, fnu_b2, fnu_w3, fnu_b3, att,
        xin, in_w, in_b, Hbf);

    for (int lay = 0; lay < 4; ++lay) {
        const float* attL = att + lay * 16;
        // fused W-gen + forward transform (independent halves)
        k_wtf<<<2560, 256, 0, stream>>>(
            fw_y + (long)lay * 2097152, fw_x + (long)lay * 2097152, attL,
            WrTy, WiTy, WinTy, WrTx, WiTx, WinTx,
            tabYF, tabXF, Hbf, Zy, Zx);
        k_mixm2<<<dim3(4, 256, 2), 256, 0, stream>>>(
            Zy, Zx, WrTy, WiTy, WinTy, WrTx, WiTx, WinTx);
        k_ti2<<<dim3(1024, 2), 256, 0, stream>>>(tabYI, tabXI, Zy, Zx, Ry, Rx);
        k_ffm<<<4096, 256, 0, stream>>>(
            Ry, Rx, W0T + lay * 16384, ff_b0 + lay * 256,
            W1T + lay * 16384, ff_b1 + lay * 64,
            ln_g + lay * 64, ln_b + lay * 64,
            Hbf, (lay == 3) ? 1 : 0);
    }
    // k_headm split into 4 px-quarters (~65us each) so layer kernels surface
    // in the top-5 dispatch table with full counters.
    for (int pq = 0; pq < 4; ++pq)
        k_headm<<<dim3(256, 5), 256, 0, stream>>>(Hbf, xin, Wcat, bcat,
                                                  c1_w, c1_b, c2_w, c2_b, out, pq);
}

// Round 10
// 1539.798 us; speedup vs baseline: 1.0599x; 1.0599x over previous
//
#include <hip/hip_runtime.h>
#include <math.h>

// ---------------------------------------------------------------------------
// OmniFluids2D forward on MI355X. bf16 dataflow + MFMA everywhere GEMM-shaped.
// Y/X spectral branches merged into double-width launches. B=4, 256^2, W=64.
// R10: k_ffm identified as dominant (180us x4, VALU 13%, HBM-latency-bound on
//     the 32KB-stride Rx gather + tail Hb RMW). Fix: ti2 z=1 writes Rx
//     pre-transposed [b][x][y][o] (write-side transpose, latency-tolerant);
//     ffm reads both R streams coalesced + hoists Hb residual loads to entry.
// ---------------------------------------------------------------------------

typedef __attribute__((ext_vector_type(8))) short sh8;
typedef __attribute__((ext_vector_type(4))) float f4;

__device__ __forceinline__ float fast_rcp(float x) {
#if defined(__has_builtin)
#if __has_builtin(__builtin_amdgcn_rcpf)
    return __builtin_amdgcn_rcpf(x);
#else
    return 1.0f / x;
#endif
#else
    return 1.0f / x;
#endif
}

__device__ __forceinline__ float gelu_f(float v) {          // exact (att only)
    return 0.5f * v * (1.0f + erff(v * 0.70710678118654752f));
}
__device__ __forceinline__ float gelu_fast(float v) {       // tanh-approx, rcp
    float s = v * (1.5957691216f + 0.0713548162f * v * v);
    float e = __expf(-s);
    return v * fast_rcp(1.0f + e);
}
__device__ __forceinline__ unsigned short f2bf(float x) {
    unsigned int u = __float_as_uint(x);
    u += 0x7fffu + ((u >> 16) & 1u);
    return (unsigned short)(u >> 16);
}
__device__ __forceinline__ float bf2f(unsigned short h) {
    return __uint_as_float(((unsigned int)h) << 16);
}

// --------------- fused front: prep (tables/weights) + att + embed ------------
__global__ __launch_bounds__(256) void k_front(
    const float* __restrict__ ff_w0, const float* __restrict__ ff_w1,
    const float* __restrict__ fa_w, const float* __restrict__ fb_w,
    const float* __restrict__ fa_b, const float* __restrict__ fb_b,
    const float* __restrict__ c1w, const float* __restrict__ c2w,
    unsigned short* __restrict__ tabBf,
    unsigned short* __restrict__ W0T, unsigned short* __restrict__ W1T,
    unsigned short* __restrict__ Wcat, float* __restrict__ bcat,
    unsigned int* __restrict__ c1p, unsigned int* __restrict__ c2p,
    const float* __restrict__ params,
    const float* __restrict__ w1, const float* __restrict__ b1,
    const float* __restrict__ w2, const float* __restrict__ b2,
    const float* __restrict__ w3, const float* __restrict__ b3,
    float* __restrict__ att,
    const float* __restrict__ xin,
    const float* __restrict__ inw, const float* __restrict__ inb,
    unsigned short* __restrict__ Hb)
{
    int bid = blockIdx.x;
    int tid = threadIdx.x;
    if (bid == 0) {
        // ---- routing attention, all layers, 128 active threads ----
        __shared__ float A1[128], A2[128], LG[4];
        int j = tid;
        for (int lay = 0; lay < 4; ++lay) {
            for (int b = 0; b < 4; ++b) {
                if (j < 128) {
                    float s = b1[lay * 128 + j];
                    for (int p = 0; p < 8; ++p)
                        s += params[b * 8 + p] * w1[(lay * 8 + p) * 128 + j];
                    A1[j] = gelu_f(s);
                }
                __syncthreads();
                if (j < 128) {
                    float s = b2[lay * 128 + j];
                    for (int q = 0; q < 128; ++q) s += A1[q] * w2[(lay * 128 + q) * 128 + j];
                    A2[j] = gelu_f(s);
                }
                __syncthreads();
                if (j < 4) {
                    float tacc = b3[lay * 4 + j];
                    for (int q = 0; q < 128; ++q) tacc += A2[q] * w3[(lay * 128 + q) * 4 + j];
                    LG[j] = tacc * 0.1f;
                }
                __syncthreads();
                if (j == 0) {
                    float mx = fmaxf(fmaxf(LG[0], LG[1]), fmaxf(LG[2], LG[3]));
                    float e0 = expf(LG[0] - mx), e1 = expf(LG[1] - mx);
                    float e2 = expf(LG[2] - mx), e3 = expf(LG[3] - mx);
                    float inv = 1.0f / (e0 + e1 + e2 + e3);
                    att[lay * 16 + b * 4 + 0] = e0 * inv;
                    att[lay * 16 + b * 4 + 1] = e1 * inv;
                    att[lay * 16 + b * 4 + 2] = e2 * inv;
                    att[lay * 16 + b * 4 + 3] = e3 * inv;
                }
                __syncthreads();
            }
        }
        return;
    }
    if (bid <= 1128) {
        // ---- prep: trig tables + weight packing ----
        int idx = (bid - 1) * 256 + tid;
        if (idx < 131072) {
            int t = idx >> 15, r = idx & 32767;
            const double PI = 3.14159265358979323846;
            const double s510 = 1.0 / sqrt(510.0);
            double v = 0.0;
            if (t == 0) {            // TAB_YF [row=2m+c][y]  (128x256)
                int row = r >> 8, y = r & 255;
                int m = row >> 1, c = row & 1;
                double ang = 2.0 * PI * (double)(m * y) / 256.0;
                v = (c == 0 ? cos(ang) : -sin(ang)) / 16.0;
            } else if (t == 1) {     // TAB_XF [row=2k+c][x]  (128x256)
                int row = r >> 8, xx = r & 255;
                int k = row >> 1, c = row & 1;
                if (c == 0) {
                    v = 0.0;
                    if (xx == 0)   v = s510;
                    if (xx == 255) v = (k & 1) ? -s510 : s510;
                } else {
                    double ang = PI * (double)(k * xx) / 255.0;
                    v = -2.0 * s510 * sin(ang);
                }
            } else if (t == 2) {     // TAB_YI [y][row=2m+c]  (256x128)
                int y = r >> 7, row = r & 127;
                int m = row >> 1, c = row & 1;
                double ang = 2.0 * PI * (double)(m * y) / 256.0;
                if (c == 0) v = (m == 0 ? 1.0 : 2.0 * cos(ang)) / 16.0;
                else        v = (m == 0 ? 0.0 : -2.0 * sin(ang) / 16.0);
            } else {                 // TAB_XI [x][row=2k+c]  (256x128)
                int xx = r >> 7, row = r & 127;
                int k = row >> 1, c = row & 1;
                double ang = PI * (double)(k * xx) / 255.0;
                if (c == 0) v = s510 * (k == 0 ? 1.0 : 2.0 * cos(ang));
                else        v = (k == 0 ? 0.0 : -2.0 * s510 * sin(ang));
            }
            tabBf[idx] = f2bf((float)v);
            return;
        }
        idx -= 131072;
        if (idx < 65536) {
            int l = idx >> 14, rem = idx & 16383;
            int n = rem >> 6, k = rem & 63;
            W0T[idx] = f2bf(ff_w0[l * 16384 + k * 256 + n]);
        } else if (idx < 131072) {
            int j = idx - 65536;
            int l = j >> 14, rem = j & 16383;
            int n = rem >> 8, k = rem & 255;
            W1T[j] = f2bf(ff_w1[l * 16384 + k * 64 + n]);
        } else if (idx < 156672) {
            int j = idx - 131072;
            int f = j / 5120, r2 = j % 5120;
            int n = r2 >> 6, k = r2 & 63;
            float v = 0.0f;
            if (n < 36)      v = fa_w[f * 2304 + k * 36 + n];
            else if (n < 70) v = fb_w[f * 2176 + k * 34 + (n - 36)];
            Wcat[j] = f2bf(v);
        } else if (idx < 157072) {
            int j = idx - 156672;
            int f = j / 80, n = j % 80;
            float v = 0.0f;
            if (n < 36)      v = fa_b[f * 36 + n];
            else if (n < 70) v = fb_b[f * 34 + (n - 36)];
            bcat[j] = v;
        } else if (idx < 157552) {
            int j = idx - 157072;         // 0..479 (workspace layout compat)
            int half = j >= 240;
            int r = j - half * 240;
            int fc = r / 6, jj = r % 6;
            const float* src = half ? c2w : c1w;
            unsigned int u = (unsigned int)f2bf(src[fc * 12 + 2 * jj])
                           | ((unsigned int)f2bf(src[fc * 12 + 2 * jj + 1]) << 16);
            (half ? c2p : c1p)[r] = u;
        }
        return;
    }
    // ---- input embedding ----
    {
        long gid = (long)(bid - 1129) * 256 + tid;   // 0..4194303
        long px = gid >> 4;
        int c4 = (int)(gid & 15) * 4;
        int y = (int)(px & 255), xi = (int)((px >> 8) & 255);
        const float* xp = xin + px * 5;
        float v[7];
        v[0] = xp[0]; v[1] = xp[1]; v[2] = xp[2]; v[3] = xp[3]; v[4] = xp[4];
        const float STEP = 6.283185307179586f / 256.0f;
        v[5] = xi * STEP;
        v[6] = y * STEP;
        float r[4];
        #pragma unroll
        for (int c = 0; c < 4; ++c) {
            int ch = c4 + c;
            float s = inb[ch];
            #pragma unroll
            for (int p = 0; p < 7; ++p) s += v[p] * inw[p * 64 + ch];
            r[c] = gelu_fast(s);
        }
        uint2 uu;
        uu.x = (unsigned int)f2bf(r[0]) | ((unsigned int)f2bf(r[1]) << 16);
        uu.y = (unsigned int)f2bf(r[2]) | ((unsigned int)f2bf(r[3]) << 16);
        *(uint2*)(Hb + px * 64 + c4) = uu;
    }
}

// ------------------------- B^T staging: global rows -> lds[n][k] -------------
__device__ __forceinline__ void stage_bt(unsigned short* lds, int pitch,
    const unsigned short* src, int rowStride, int K, int tid)
{
    int pairs = K >> 1;
    int tasks = pairs * 8;
    for (int idx = tid; idx < tasks; idx += 256) {
        int p = idx & (pairs - 1);
        int cg = idx / pairs;
        const unsigned short* s0 = src + (long)(2 * p) * rowStride + cg * 8;
        sh8 r0 = *(const sh8*)s0;
        sh8 r1 = *(const sh8*)(s0 + rowStride);
        unsigned short* dbase = lds + cg * 8 * pitch + 2 * p;
        #pragma unroll
        for (int j = 0; j < 8; ++j) {
            unsigned int u = (unsigned int)(unsigned short)r0[j]
                           | ((unsigned int)(unsigned short)r1[j] << 16);
            *(unsigned int*)(dbase + j * pitch) = u;
        }
    }
}

// --------------- fused W-generation + forward transform ----------------------
// bid < 512: wfuse half. bid >= 512: tf2 half -> Z in [b][r][s][o] layout.
__global__ __launch_bounds__(256) void k_wtf(
    const float* __restrict__ fwY, const float* __restrict__ fwX,
    const float* __restrict__ att,
    unsigned short* __restrict__ WrTy, unsigned short* __restrict__ WiTy,
    unsigned short* __restrict__ WinTy,
    unsigned short* __restrict__ WrTx, unsigned short* __restrict__ WiTx,
    unsigned short* __restrict__ WinTx,
    const unsigned short* __restrict__ tabY, const unsigned short* __restrict__ tabX,
    const unsigned short* __restrict__ Hb,
    unsigned short* __restrict__ Zy, unsigned short* __restrict__ Zx)
{
    __shared__ __align__(16) unsigned char smem[34816];  // max(tf2 34816, wfuse 33280)
    int bid = blockIdx.x;
    int tid = threadIdx.x;
    if (bid < 512) {
        // ---- wfuse ----
        int o = bid & 63, b = (bid >> 6) & 3, z = bid >> 8;
        const float* fw = z ? fwX : fwY;
        unsigned short* WrT  = z ? WrTx  : WrTy;
        unsigned short* WiT  = z ? WiTx  : WiTy;
        unsigned short* WinT = z ? WinTx : WinTy;
        float av[4];
        av[0] = att[b * 4 + 0]; av[1] = att[b * 4 + 1];
        av[2] = att[b * 4 + 2]; av[3] = att[b * 4 + 3];
        float acc[32];
        #pragma unroll
        for (int j = 0; j < 32; ++j) acc[j] = 0.0f;
        long toff = (long)(tid >> 7) * 8192 + o * 128 + (tid & 127);
        for (int k = 0; k < 4; ++k) {
            const float* p = fw + (long)k * 524288 + toff;
            float a = av[k];
            #pragma unroll
            for (int j = 0; j < 32; ++j) acc[j] += a * p[j * 16384];
        }
        float* ldsR = (float*)smem;              // 64*65*4 = 16640 B
        float* ldsI = (float*)(smem + 16640);    // +16640 = 33280 B total
        int m = (tid & 127) >> 1, c = tid & 1;
        int ib = tid >> 7;
        #pragma unroll
        for (int j = 0; j < 32; ++j) {
            int i = j * 2 + ib;
            (c ? ldsI : ldsR)[m * 65 + i] = acc[j];
        }
        __syncthreads();
        long ob = (long)b * 262144 + o * 64;   // + m*4096 + i
        #pragma unroll
        for (int it = 0; it < 16; ++it) {
            int idx = it * 256 + tid;
            int mm = idx >> 6, ii = idx & 63;
            float rr = ldsR[mm * 65 + ii], im = ldsI[mm * 65 + ii];
            long a = ob + (long)mm * 4096 + ii;
            WrT[a]  = f2bf(rr);
            WiT[a]  = f2bf(im);
            WinT[a] = f2bf(-im);
        }
        return;
    }
    // ---- tf2 ----
    unsigned short* ldsB = (unsigned short*)smem;   // 64*272*2 = 34816 B
    int g2 = bid - 512;
    int br = g2 >> 10, g = g2 & 1023;
    int b = g >> 8, s = g & 255;
    const unsigned short* tab = br ? tabX : tabY;
    unsigned short* Zo = br ? Zx : Zy;
    long sLo = br ? 64L : 16384L;
    int rowStride = br ? 16384 : 64;
    const unsigned short* src = Hb + (long)b * 4194304 + (long)s * sLo;
    stage_bt(ldsB, 272, src, rowStride, 256, tid);
    __syncthreads();
    int w = tid >> 6, lane = tid & 63, q = lane >> 4, ln = lane & 15;
    f4 acc[2][4];
    #pragma unroll
    for (int mi = 0; mi < 2; ++mi)
        #pragma unroll
        for (int ni = 0; ni < 4; ++ni) acc[mi][ni] = (f4){0.f, 0.f, 0.f, 0.f};
    for (int kc = 0; kc < 256; kc += 32) {
        sh8 a[2], bf[4];
        #pragma unroll
        for (int mi = 0; mi < 2; ++mi)
            a[mi] = *(const sh8*)(tab + (w * 32 + mi * 16 + ln) * 256 + kc + q * 8);
        #pragma unroll
        for (int ni = 0; ni < 4; ++ni)
            bf[ni] = *(const sh8*)(ldsB + (ni * 16 + ln) * 272 + kc + q * 8);
        #pragma unroll
        for (int mi = 0; mi < 2; ++mi)
            #pragma unroll
            for (int ni = 0; ni < 4; ++ni)
                acc[mi][ni] = __builtin_amdgcn_mfma_f32_16x16x32_bf16(
                    a[mi], bf[ni], acc[mi][ni], 0, 0, 0);
    }
    // write Z[b][r][s][o]
    long zB = (long)b * 2097152 + (long)s * 64;
    #pragma unroll
    for (int mi = 0; mi < 2; ++mi)
        #pragma unroll
        for (int ni = 0; ni < 4; ++ni)
            #pragma unroll
            for (int reg = 0; reg < 4; ++reg) {
                int r = w * 32 + mi * 16 + q * 4 + reg;
                Zo[zB + (long)r * 16384 + ni * 16 + ln] = f2bf(acc[mi][ni][reg]);
            }
}

// ------------------------- MFMA complex mode-mix, both branches --------------
// Z layout [b][r][s][o]: freq rows 2m (Re) / 2m+1 (Im) are 16384-sh planes;
// lane stride along s is 64 sh (128 B) -> fully-coalesced reads and writes.
__global__ __launch_bounds__(256) void k_mixm2(
    unsigned short* Zy, unsigned short* Zx,
    const unsigned short* __restrict__ WrTy, const unsigned short* __restrict__ WiTy,
    const unsigned short* __restrict__ WinTy,
    const unsigned short* __restrict__ WrTx, const unsigned short* __restrict__ WiTx,
    const unsigned short* __restrict__ WinTx)
{
    int xt = blockIdx.x, g = blockIdx.y, z = blockIdx.z;
    unsigned short* Z = z ? Zx : Zy;
    const unsigned short* WrT  = z ? WrTx  : WrTy;
    const unsigned short* WiT  = z ? WiTx  : WiTy;
    const unsigned short* WinT = z ? WinTx : WinTy;
    int b = g >> 6, m = g & 63;
    int tid = threadIdx.x, w = tid >> 6, lane = tid & 63, q = lane >> 4, ln = lane & 15;
    long zBr = (long)b * 2097152 + (long)(2 * m) * 16384;   // Re plane; Im at +16384
    long wB = (long)b * 262144 + (long)m * 4096;
    int s0 = xt * 64 + w * 16;
    f4 aR[4], aI[4];
    #pragma unroll
    for (int nt = 0; nt < 4; ++nt) { aR[nt] = (f4){0.f,0.f,0.f,0.f}; aI[nt] = (f4){0.f,0.f,0.f,0.f}; }
    for (int kc = 0; kc < 64; kc += 32) {
        sh8 zr = *(const sh8*)(Z + zBr + (long)(s0 + ln) * 64 + kc + q * 8);
        sh8 zi = *(const sh8*)(Z + zBr + 16384 + (long)(s0 + ln) * 64 + kc + q * 8);
        #pragma unroll
        for (int nt = 0; nt < 4; ++nt) {
            int o = nt * 16 + ln;
            sh8 wr = *(const sh8*)(WrT + wB + o * 64 + kc + q * 8);
            sh8 wi = *(const sh8*)(WiT + wB + o * 64 + kc + q * 8);
            sh8 wn = *(const sh8*)(WinT + wB + o * 64 + kc + q * 8);
            aR[nt] = __builtin_amdgcn_mfma_f32_16x16x32_bf16(zr, wr, aR[nt], 0, 0, 0);
            aR[nt] = __builtin_amdgcn_mfma_f32_16x16x32_bf16(zi, wn, aR[nt], 0, 0, 0);
            aI[nt] = __builtin_amdgcn_mfma_f32_16x16x32_bf16(zr, wi, aI[nt], 0, 0, 0);
            aI[nt] = __builtin_amdgcn_mfma_f32_16x16x32_bf16(zi, wr, aI[nt], 0, 0, 0);
        }
    }
    #pragma unroll
    for (int nt = 0; nt < 4; ++nt)
        #pragma unroll
        for (int reg = 0; reg < 4; ++reg) {
            int s = s0 + q * 4 + reg;
            long a = zBr + (long)s * 64 + nt * 16 + ln;
            Z[a]          = f2bf(aR[nt][reg]);
            Z[a + 16384]  = f2bf(aI[nt][reg]);
        }
}

// ------------------------- MFMA inverse transform, both branches -------------
// Z layout [b][r][s][o]: stage with rowStride 16384 at base +s*64.
// BOTH branches now write R in [b][x][y][o] layout:
//   z=0 (Ry): s = x, rows r2 = y -> addr = b*4M + s*16384 + r2*64 + o (as before)
//   z=1 (Rx): s = y, rows r2 = x -> addr = b*4M + r2*16384 + s*64 + o
//             (write-side transpose: scattered stores are latency-tolerant;
//              k_ffm's reads of Rx become fully coalesced)
__global__ __launch_bounds__(256) void k_ti2(
    const unsigned short* __restrict__ tabY, const unsigned short* __restrict__ tabX,
    const unsigned short* __restrict__ Zy, const unsigned short* __restrict__ Zx,
    unsigned short* __restrict__ Ry, unsigned short* __restrict__ Rx)
{
    __shared__ __align__(16) unsigned short ldsB[64 * 144];
    int g = blockIdx.x, br = blockIdx.y;
    int b = g >> 8, s = g & 255;
    const unsigned short* tab = br ? tabX : tabY;
    const unsigned short* Zl  = br ? Zx : Zy;
    unsigned short* Ro = br ? Rx : Ry;
    int tid = threadIdx.x;
    const unsigned short* src = Zl + (long)b * 2097152 + (long)s * 64;
    stage_bt(ldsB, 144, src, 16384, 128, tid);
    __syncthreads();
    int w = tid >> 6, lane = tid & 63, q = lane >> 4, ln = lane & 15;
    f4 acc[4][4];
    #pragma unroll
    for (int mi = 0; mi < 4; ++mi)
        #pragma unroll
        for (int ni = 0; ni < 4; ++ni) acc[mi][ni] = (f4){0.f, 0.f, 0.f, 0.f};
    for (int kc = 0; kc < 128; kc += 32) {
        sh8 a[4], bf[4];
        #pragma unroll
        for (int mi = 0; mi < 4; ++mi)
            a[mi] = *(const sh8*)(tab + (w * 64 + mi * 16 + ln) * 128 + kc + q * 8);
        #pragma unroll
        for (int ni = 0; ni < 4; ++ni)
            bf[ni] = *(const sh8*)(ldsB + (ni * 16 + ln) * 144 + kc + q * 8);
        #pragma unroll
        for (int mi = 0; mi < 4; ++mi)
            #pragma unroll
            for (int ni = 0; ni < 4; ++ni)
                acc[mi][ni] = __builtin_amdgcn_mfma_f32_16x16x32_bf16(
                    a[mi], bf[ni], acc[mi][ni], 0, 0, 0);
    }
    long rB0 = (long)b * 4194304;
    #pragma unroll
    for (int mi = 0; mi < 4; ++mi)
        #pragma unroll
        for (int ni = 0; ni < 4; ++ni)
            #pragma unroll
            for (int reg = 0; reg < 4; ++reg) {
                int r2 = w * 64 + mi * 16 + q * 4 + reg;
                long a;
                if (br) a = rB0 + (long)r2 * 16384 + (long)s * 64 + ni * 16 + ln;
                else    a = rB0 + (long)s * 16384 + (long)r2 * 64 + ni * 16 + ln;
                Ro[a] = f2bf(acc[mi][ni][reg]);
            }
}

// ------------------------- MFMA fused FeedForward + LN -----------------------
// A = bf16(Ry + Rx) built in registers; residual stream in bf16 (Hb).
// R10: Rx is now [b][x][y][o] (same as Ry) -> both streams coalesced;
//      Hb residual loads hoisted to kernel entry (hidden under phase 1).
__global__ __launch_bounds__(256) void k_ffm(
    const unsigned short* __restrict__ Ry, const unsigned short* __restrict__ Rx,
    const unsigned short* __restrict__ W0T, const float* __restrict__ b0,
    const unsigned short* __restrict__ W1T, const float* __restrict__ b1,
    const float* __restrict__ g1, const float* __restrict__ be1,
    unsigned short* __restrict__ Hb, int last)
{
    __shared__ __align__(16) unsigned short T[64 * 264];
    int m0 = blockIdx.x * 64;
    int tid = threadIdx.x, w = tid >> 6, lane = tid & 63, q = lane >> 4, ln = lane & 15;
    int row = m0 + w * 16 + ln;
    const unsigned short* ryp = Ry + (long)row * 64;
    const unsigned short* rxp = Rx + (long)row * 64;
    // hoisted residual loads (issued early; hidden under phase 1)
    float hbold[16];
    if (!last) {
        #pragma unroll
        for (int reg = 0; reg < 4; ++reg)
            #pragma unroll
            for (int nt = 0; nt < 4; ++nt)
                hbold[reg * 4 + nt] =
                    bf2f(Hb[(long)(m0 + w * 16 + q * 4 + reg) * 64 + nt * 16 + ln]);
    }
    // phase 1: T = relu((Ry+Rx) @ W0 + b0), rows w*16..+15, N=256
    {
        f4 acc1[16];
        #pragma unroll
        for (int nt = 0; nt < 16; ++nt) acc1[nt] = (f4){0.f, 0.f, 0.f, 0.f};
        for (int kc = 0; kc < 64; kc += 32) {
            sh8 ry = *(const sh8*)(ryp + kc + q * 8);
            sh8 rx = *(const sh8*)(rxp + kc + q * 8);
            sh8 a;
            #pragma unroll
            for (int j = 0; j < 8; ++j)
                a[j] = (short)f2bf(bf2f((unsigned short)ry[j]) + bf2f((unsigned short)rx[j]));
            #pragma unroll
            for (int nt = 0; nt < 16; ++nt) {
                sh8 bf = *(const sh8*)(W0T + (nt * 16 + ln) * 64 + kc + q * 8);
                acc1[nt] = __builtin_amdgcn_mfma_f32_16x16x32_bf16(a, bf, acc1[nt], 0, 0, 0);
            }
        }
        #pragma unroll
        for (int nt = 0; nt < 16; ++nt) {
            int n = nt * 16 + ln;
            float bias = b0[n];
            #pragma unroll
            for (int reg = 0; reg < 4; ++reg) {
                int m = w * 16 + q * 4 + reg;
                T[m * 264 + n] = f2bf(fmaxf(acc1[nt][reg] + bias, 0.0f));
            }
        }
    }
    // phase 2 (intra-wave LDS dep): t = T @ W1 + b1, then LN + residual
    f4 acc2[4];
    #pragma unroll
    for (int nt = 0; nt < 4; ++nt) acc2[nt] = (f4){0.f, 0.f, 0.f, 0.f};
    for (int kc = 0; kc < 256; kc += 32) {
        sh8 a = *(const sh8*)(T + (w * 16 + ln) * 264 + kc + q * 8);
        #pragma unroll
        for (int nt = 0; nt < 4; ++nt) {
            sh8 bf = *(const sh8*)(W1T + (nt * 16 + ln) * 256 + kc + q * 8);
            acc2[nt] = __builtin_amdgcn_mfma_f32_16x16x32_bf16(a, bf, acc2[nt], 0, 0, 0);
        }
    }
    float bia[4], gg[4], bb4[4];
    #pragma unroll
    for (int nt = 0; nt < 4; ++nt) {
        int n = nt * 16 + ln;
        bia[nt] = b1[n]; gg[nt] = g1[n]; bb4[nt] = be1[n];
    }
    #pragma unroll
    for (int reg = 0; reg < 4; ++reg) {
        float t[4];
        float s = 0.f, qs = 0.f;
        #pragma unroll
        for (int nt = 0; nt < 4; ++nt) {
            t[nt] = acc2[nt][reg] + bia[nt];
            s += t[nt]; qs += t[nt] * t[nt];
        }
        #pragma unroll
        for (int d = 1; d < 16; d <<= 1) {
            s  += __shfl_xor(s, d, 64);
            qs += __shfl_xor(qs, d, 64);
        }
        float mean = s * (1.0f / 64.0f);
        float var  = qs * (1.0f / 64.0f) - mean * mean;
        float inv  = rsqrtf(var + 1e-5f);
        int m = w * 16 + q * 4 + reg;
        long base = (long)(m0 + m) * 64;
        #pragma unroll
        for (int nt = 0; nt < 4; ++nt) {
            int n = nt * 16 + ln;
            float v = (t[nt] - mean) * inv * gg[nt] + bb4[nt];
            float hv;
            if (last) hv = gelu_fast(v);
            else      hv = hbold[reg * 4 + nt] + v;
            Hb[base + n] = f2bf(hv);
        }
    }
}

// ------------------------- output heads (MFMA ha + fp32 conv) ----------------
// px-quarter per dispatch (pxQ): dim3(256,5) x 4 launches. Same math as R4.
__global__ __launch_bounds__(256) void k_headm(
    const unsigned short* __restrict__ Hb, const float* __restrict__ x0,
    const unsigned short* __restrict__ Wcat, const float* __restrict__ bcat,
    const float* __restrict__ c1w, const float* __restrict__ c1b,
    const float* __restrict__ c2w, const float* __restrict__ c2b,
    float* __restrict__ out, int pxQ)
{
    __shared__ unsigned short ha[256 * 74];   // [px][j], pitch 74 (gcd(37,32)=1)
    int tid = threadIdx.x;
    int f = blockIdx.y;
    long px0 = (long)(pxQ * 256 + blockIdx.x) * 256;
    int w = tid >> 6, lane = tid & 63, q = lane >> 4, ln = lane & 15;

    // ha-GEMM, one mi (16 rows) at a time: acc[5] live, not acc[4][5]
    #pragma unroll
    for (int mi = 0; mi < 4; ++mi) {
        f4 acc[5];
        #pragma unroll
        for (int nt = 0; nt < 5; ++nt) acc[nt] = (f4){0.f, 0.f, 0.f, 0.f};
        #pragma unroll
        for (int kc = 0; kc < 2; ++kc) {
            sh8 a = *(const sh8*)(Hb + (px0 + w * 64 + mi * 16 + ln) * 64
                                   + kc * 32 + q * 8);
            #pragma unroll
            for (int nt = 0; nt < 5; ++nt) {
                sh8 bf = *(const sh8*)(Wcat + f * 5120 + (nt * 16 + ln) * 64
                                        + kc * 32 + q * 8);
                acc[nt] = __builtin_amdgcn_mfma_f32_16x16x32_bf16(a, bf, acc[nt], 0, 0, 0);
            }
        }
        #pragma unroll
        for (int nt = 0; nt < 5; ++nt) {
            int n = nt * 16 + ln;
            if (n < 70) {
                float bias = bcat[f * 80 + n];
                #pragma unroll
                for (int reg = 0; reg < 4; ++reg) {
                    int m = w * 64 + mi * 16 + q * 4 + reg;
                    ha[m * 74 + n] = f2bf(gelu_fast(acc[nt][reg] + bias));
                }
            }
        }
    }
    __syncthreads();

    // conv phase: one pixel per thread, fp32 FMA.
    float u2[10];
    float b2v = c2b[f];
    #pragma unroll
    for (int d = 0; d < 10; ++d) u2[d] = b2v;
    #pragma unroll
    for (int h = 0; h < 2; ++h) {
        float hw[40];   // hv[30h .. 30h+39]
        #pragma unroll
        for (int i = 0; i < 20; ++i) {
            unsigned int u = *(const unsigned int*)(ha + tid * 74 + h * 30 + 2 * i);
            hw[2 * i]     = __uint_as_float(u << 16);
            hw[2 * i + 1] = __uint_as_float(u & 0xffff0000u);
        }
        #pragma unroll 1
        for (int c = 0; c < 8; ++c) {
            int fc = f * 8 + c;
            float w1r[12], w2r[12];   // wave-uniform -> SGPRs
            #pragma unroll
            for (int j = 0; j < 12; ++j) {
                w1r[j] = c1w[fc * 12 + j];
                w2r[j] = c2w[fc * 12 + j];
            }
            float bc = c1b[fc];
            #pragma unroll
            for (int pl = 0; pl < 15; ++pl) {
                const int p = h * 15 + pl;     // compile-time after unroll
                float s = bc;
                #pragma unroll
                for (int j = 0; j < 12; ++j)
                    s = fmaf(hw[2 * pl + j], w1r[j], s);
                float g = gelu_fast(s);
                #pragma unroll
                for (int d = 0; d < 10; ++d) {
                    const int j2 = p - 2 * d;  // compile-time bounds
                    if (j2 >= 0 && j2 < 12)
                        u2[d] = fmaf(g, w2r[j2], u2[d]);
                }
            }
        }
    }
    long px = px0 + tid;
    float xv = x0[px * 5 + f];
    #pragma unroll
    for (int d = 0; d < 10; ++d)
        out[px * 50 + f * 10 + d] = xv + u2[d] * (float)(d + 1) * 0.1f;
}

// ---------------------------------------------------------------------------
extern "C" void kernel_launch(void* const* d_in, const int* in_sizes, int n_in,
                              void* d_out, int out_size, void* d_ws, size_t ws_size,
                              hipStream_t stream) {
    (void)in_sizes; (void)n_in; (void)out_size; (void)ws_size;
    const float* xin    = (const float*)d_in[0];
    const float* params = (const float*)d_in[1];
    const float* in_w   = (const float*)d_in[2];
    const float* in_b   = (const float*)d_in[3];
    const float* fnu_w1 = (const float*)d_in[4];
    const float* fnu_b1 = (const float*)d_in[5];
    const float* fnu_w2 = (const float*)d_in[6];
    const float* fnu_b2 = (const float*)d_in[7];
    const float* fnu_w3 = (const float*)d_in[8];
    const float* fnu_b3 = (const float*)d_in[9];
    const float* fw_y   = (const float*)d_in[10];
    const float* fw_x   = (const float*)d_in[11];
    const float* ff_w0  = (const float*)d_in[12];
    const float* ff_b0  = (const float*)d_in[13];
    const float* ff_w1  = (const float*)d_in[14];
    const float* ff_b1  = (const float*)d_in[15];
    const float* ln_g   = (const float*)d_in[16];
    const float* ln_b   = (const float*)d_in[17];
    const float* fa_w   = (const float*)d_in[18];
    const float* fa_b   = (const float*)d_in[19];
    const float* fb_w   = (const float*)d_in[20];
    const float* fb_b   = (const float*)d_in[21];
    const float* c1_w   = (const float*)d_in[22];
    const float* c1_b   = (const float*)d_in[23];
    const float* c2_w   = (const float*)d_in[24];
    const float* c2_b   = (const float*)d_in[25];
    float* out = (float*)d_out;
    float* ws  = (float*)d_ws;

    // workspace (float offsets), total ~41.0M floats (~164 MB)
    unsigned short* tabBf = (unsigned short*)(ws + 0);        // 131072 sh
    unsigned short* tabYF = tabBf;
    unsigned short* tabXF = tabBf + 32768;
    unsigned short* tabYI = tabBf + 65536;
    unsigned short* tabXI = tabBf + 98304;
    unsigned short* W0T   = (unsigned short*)(ws + 65536);    // 65536 sh
    unsigned short* W1T   = (unsigned short*)(ws + 98304);    // 65536 sh
    unsigned short* Wcat  = (unsigned short*)(ws + 131072);   // 25600 sh
    float* bcat = ws + 143872;                                 // 400
    float* att  = ws + 144272;                                 // 64
    unsigned int* c1p = (unsigned int*)(ws + 144336);          // 240 (layout compat)
    unsigned int* c2p = (unsigned int*)(ws + 144576);          // 240 (layout compat)
    unsigned short* Hbf = (unsigned short*)(ws + 144816);      // 16.8M sh
    // WRy..WIx fp32 slots (ws+8533424..) unused since R5 (wfuse writes bf16 direct)
    unsigned short* WrTy  = (unsigned short*)(ws + 12727728);  // 1M sh each
    unsigned short* WiTy  = (unsigned short*)(ws + 13252016);
    unsigned short* WinTy = (unsigned short*)(ws + 13776304);
    unsigned short* WrTx  = (unsigned short*)(ws + 14300592);
    unsigned short* WiTx  = (unsigned short*)(ws + 14824880);
    unsigned short* WinTx = (unsigned short*)(ws + 15349168);
    unsigned short* Zy    = (unsigned short*)(ws + 15873456);  // 8.4M sh
    unsigned short* Zx    = (unsigned short*)(ws + 20067760);  // 8.4M sh
    unsigned short* Ry    = (unsigned short*)(ws + 24262064);  // 16.8M sh
    unsigned short* Rx    = (unsigned short*)(ws + 32650672);  // 16.8M sh

    // fused front: prep + att + embed (independent) in one dispatch
    k_front<<<17513, 256, 0, stream>>>(
        ff_w0, ff_w1, fa_w, fb_w, fa_b, fb_b, c1_w, c2_w,
        tabBf, W0T, W1T, Wcat, bcat, c1p, c2p,
        params, fnu_w1, fnu_b1, fnu_w2, fnu_b2, fnu_w3, fnu_b3, att,
        xin, in_w, in_b, Hbf);

    for (int lay = 0; lay < 4; ++lay) {
        const float* attL = att + lay * 16;
        // fused W-gen + forward transform (independent halves)
        k_wtf<<<2560, 256, 0, stream>>>(
            fw_y + (long)lay * 2097152, fw_x + (long)lay * 2097152, attL,
            WrTy, WiTy, WinTy, WrTx, WiTx, WinTx,
            tabYF, tabXF, Hbf, Zy, Zx);
        k_mixm2<<<dim3(4, 256, 2), 256, 0, stream>>>(
            Zy, Zx, WrTy, WiTy, WinTy, WrTx, WiTx, WinTx);
        k_ti2<<<dim3(1024, 2), 256, 0, stream>>>(tabYI, tabXI, Zy, Zx, Ry, Rx);
        k_ffm<<<4096, 256, 0, stream>>>(
            Ry, Rx, W0T + lay * 16384, ff_b0 + lay * 256,
            W1T + lay * 16384, ff_b1 + lay * 64,
            ln_g + lay * 64, ln_b + lay * 64,
            Hbf, (lay == 3) ? 1 : 0);
    }
    // k_headm split into 4 px-quarters (~65us each): keeps layer kernels
    // visible in the top-5 dispatch table with full counters.
    for (int pq = 0; pq < 4; ++pq)
        k_headm<<<dim3(256, 5), 256, 0, stream>>>(Hbf, xin, Wcat, bcat,
                                                  c1_w, c1_b, c2_w, c2_b, out, pq);
}

// Round 12
// 1324.371 us; speedup vs baseline: 1.2323x; 1.1627x over previous
//
#include <hip/hip_runtime.h>
#include <math.h>

// ---------------------------------------------------------------------------
// OmniFluids2D forward on MI355X. bf16 dataflow + MFMA everywhere GEMM-shaped.
// Y/X spectral branches merged into double-width launches. B=4, 256^2, W=64.
// R11/R12: k_ffm restructured for memory-level parallelism: 1024 blocks x 4
//     row-tiles with register prefetch of next tile's Ry/Rx (loads in flight
//     across current tile's MFMA chain). Decisive test of latency-bound
//     theory (VALU 15%, Occ 22%, 560 GB/s on 83MB in R10).
//     R12 = R11 resubmit (container infra failure); guarded tile rotation.
// ---------------------------------------------------------------------------

typedef __attribute__((ext_vector_type(8))) short sh8;
typedef __attribute__((ext_vector_type(4))) float f4;

__device__ __forceinline__ float fast_rcp(float x) {
#if defined(__has_builtin)
#if __has_builtin(__builtin_amdgcn_rcpf)
    return __builtin_amdgcn_rcpf(x);
#else
    return 1.0f / x;
#endif
#else
    return 1.0f / x;
#endif
}

__device__ __forceinline__ float gelu_f(float v) {          // exact (att only)
    return 0.5f * v * (1.0f + erff(v * 0.70710678118654752f));
}
__device__ __forceinline__ float gelu_fast(float v) {       // tanh-approx, rcp
    float s = v * (1.5957691216f + 0.0713548162f * v * v);
    float e = __expf(-s);
    return v * fast_rcp(1.0f + e);
}
__device__ __forceinline__ unsigned short f2bf(float x) {
    unsigned int u = __float_as_uint(x);
    u += 0x7fffu + ((u >> 16) & 1u);
    return (unsigned short)(u >> 16);
}
__device__ __forceinline__ float bf2f(unsigned short h) {
    return __uint_as_float(((unsigned int)h) << 16);
}

// --------------- fused front: prep (tables/weights) + att + embed ------------
__global__ __launch_bounds__(256) void k_front(
    const float* __restrict__ ff_w0, const float* __restrict__ ff_w1,
    const float* __restrict__ fa_w, const float* __restrict__ fb_w,
    const float* __restrict__ fa_b, const float* __restrict__ fb_b,
    const float* __restrict__ c1w, const float* __restrict__ c2w,
    unsigned short* __restrict__ tabBf,
    unsigned short* __restrict__ W0T, unsigned short* __restrict__ W1T,
    unsigned short* __restrict__ Wcat, float* __restrict__ bcat,
    unsigned int* __restrict__ c1p, unsigned int* __restrict__ c2p,
    const float* __restrict__ params,
    const float* __restrict__ w1, const float* __restrict__ b1,
    const float* __restrict__ w2, const float* __restrict__ b2,
    const float* __restrict__ w3, const float* __restrict__ b3,
    float* __restrict__ att,
    const float* __restrict__ xin,
    const float* __restrict__ inw, const float* __restrict__ inb,
    unsigned short* __restrict__ Hb)
{
    int bid = blockIdx.x;
    int tid = threadIdx.x;
    if (bid == 0) {
        // ---- routing attention, all layers, 128 active threads ----
        __shared__ float A1[128], A2[128], LG[4];
        int j = tid;
        for (int lay = 0; lay < 4; ++lay) {
            for (int b = 0; b < 4; ++b) {
                if (j < 128) {
                    float s = b1[lay * 128 + j];
                    for (int p = 0; p < 8; ++p)
                        s += params[b * 8 + p] * w1[(lay * 8 + p) * 128 + j];
                    A1[j] = gelu_f(s);
                }
                __syncthreads();
                if (j < 128) {
                    float s = b2[lay * 128 + j];
                    for (int q = 0; q < 128; ++q) s += A1[q] * w2[(lay * 128 + q) * 128 + j];
                    A2[j] = gelu_f(s);
                }
                __syncthreads();
                if (j < 4) {
                    float tacc = b3[lay * 4 + j];
                    for (int q = 0; q < 128; ++q) tacc += A2[q] * w3[(lay * 128 + q) * 4 + j];
                    LG[j] = tacc * 0.1f;
                }
                __syncthreads();
                if (j == 0) {
                    float mx = fmaxf(fmaxf(LG[0], LG[1]), fmaxf(LG[2], LG[3]));
                    float e0 = expf(LG[0] - mx), e1 = expf(LG[1] - mx);
                    float e2 = expf(LG[2] - mx), e3 = expf(LG[3] - mx);
                    float inv = 1.0f / (e0 + e1 + e2 + e3);
                    att[lay * 16 + b * 4 + 0] = e0 * inv;
                    att[lay * 16 + b * 4 + 1] = e1 * inv;
                    att[lay * 16 + b * 4 + 2] = e2 * inv;
                    att[lay * 16 + b * 4 + 3] = e3 * inv;
                }
                __syncthreads();
            }
        }
        return;
    }
    if (bid <= 1128) {
        // ---- prep: trig tables + weight packing ----
        int idx = (bid - 1) * 256 + tid;
        if (idx < 131072) {
            int t = idx >> 15, r = idx & 32767;
            const double PI = 3.14159265358979323846;
            const double s510 = 1.0 / sqrt(510.0);
            double v = 0.0;
            if (t == 0) {            // TAB_YF [row=2m+c][y]  (128x256)
                int row = r >> 8, y = r & 255;
                int m = row >> 1, c = row & 1;
                double ang = 2.0 * PI * (double)(m * y) / 256.0;
                v = (c == 0 ? cos(ang) : -sin(ang)) / 16.0;
            } else if (t == 1) {     // TAB_XF [row=2k+c][x]  (128x256)
                int row = r >> 8, xx = r & 255;
                int k = row >> 1, c = row & 1;
                if (c == 0) {
                    v = 0.0;
                    if (xx == 0)   v = s510;
                    if (xx == 255) v = (k & 1) ? -s510 : s510;
                } else {
                    double ang = PI * (double)(k * xx) / 255.0;
                    v = -2.0 * s510 * sin(ang);
                }
            } else if (t == 2) {     // TAB_YI [y][row=2m+c]  (256x128)
                int y = r >> 7, row = r & 127;
                int m = row >> 1, c = row & 1;
                double ang = 2.0 * PI * (double)(m * y) / 256.0;
                if (c == 0) v = (m == 0 ? 1.0 : 2.0 * cos(ang)) / 16.0;
                else        v = (m == 0 ? 0.0 : -2.0 * sin(ang) / 16.0);
            } else {                 // TAB_XI [x][row=2k+c]  (256x128)
                int xx = r >> 7, row = r & 127;
                int k = row >> 1, c = row & 1;
                double ang = PI * (double)(k * xx) / 255.0;
                if (c == 0) v = s510 * (k == 0 ? 1.0 : 2.0 * cos(ang));
                else        v = (k == 0 ? 0.0 : -2.0 * s510 * sin(ang));
            }
            tabBf[idx] = f2bf((float)v);
            return;
        }
        idx -= 131072;
        if (idx < 65536) {
            int l = idx >> 14, rem = idx & 16383;
            int n = rem >> 6, k = rem & 63;
            W0T[idx] = f2bf(ff_w0[l * 16384 + k * 256 + n]);
        } else if (idx < 131072) {
            int j = idx - 65536;
            int l = j >> 14, rem = j & 16383;
            int n = rem >> 8, k = rem & 255;
            W1T[j] = f2bf(ff_w1[l * 16384 + k * 64 + n]);
        } else if (idx < 156672) {
            int j = idx - 131072;
            int f = j / 5120, r2 = j % 5120;
            int n = r2 >> 6, k = r2 & 63;
            float v = 0.0f;
            if (n < 36)      v = fa_w[f * 2304 + k * 36 + n];
            else if (n < 70) v = fb_w[f * 2176 + k * 34 + (n - 36)];
            Wcat[j] = f2bf(v);
        } else if (idx < 157072) {
            int j = idx - 156672;
            int f = j / 80, n = j % 80;
            float v = 0.0f;
            if (n < 36)      v = fa_b[f * 36 + n];
            else if (n < 70) v = fb_b[f * 34 + (n - 36)];
            bcat[j] = v;
        } else if (idx < 157552) {
            int j = idx - 157072;         // 0..479 (workspace layout compat)
            int half = j >= 240;
            int r = j - half * 240;
            int fc = r / 6, jj = r % 6;
            const float* src = half ? c2w : c1w;
            unsigned int u = (unsigned int)f2bf(src[fc * 12 + 2 * jj])
                           | ((unsigned int)f2bf(src[fc * 12 + 2 * jj + 1]) << 16);
            (half ? c2p : c1p)[r] = u;
        }
        return;
    }
    // ---- input embedding ----
    {
        long gid = (long)(bid - 1129) * 256 + tid;   // 0..4194303
        long px = gid >> 4;
        int c4 = (int)(gid & 15) * 4;
        int y = (int)(px & 255), xi = (int)((px >> 8) & 255);
        const float* xp = xin + px * 5;
        float v[7];
        v[0] = xp[0]; v[1] = xp[1]; v[2] = xp[2]; v[3] = xp[3]; v[4] = xp[4];
        const float STEP = 6.283185307179586f / 256.0f;
        v[5] = xi * STEP;
        v[6] = y * STEP;
        float r[4];
        #pragma unroll
        for (int c = 0; c < 4; ++c) {
            int ch = c4 + c;
            float s = inb[ch];
            #pragma unroll
            for (int p = 0; p < 7; ++p) s += v[p] * inw[p * 64 + ch];
            r[c] = gelu_fast(s);
        }
        uint2 uu;
        uu.x = (unsigned int)f2bf(r[0]) | ((unsigned int)f2bf(r[1]) << 16);
        uu.y = (unsigned int)f2bf(r[2]) | ((unsigned int)f2bf(r[3]) << 16);
        *(uint2*)(Hb + px * 64 + c4) = uu;
    }
}

// ------------------------- B^T staging: global rows -> lds[n][k] -------------
__device__ __forceinline__ void stage_bt(unsigned short* lds, int pitch,
    const unsigned short* src, int rowStride, int K, int tid)
{
    int pairs = K >> 1;
    int tasks = pairs * 8;
    for (int idx = tid; idx < tasks; idx += 256) {
        int p = idx & (pairs - 1);
        int cg = idx / pairs;
        const unsigned short* s0 = src + (long)(2 * p) * rowStride + cg * 8;
        sh8 r0 = *(const sh8*)s0;
        sh8 r1 = *(const sh8*)(s0 + rowStride);
        unsigned short* dbase = lds + cg * 8 * pitch + 2 * p;
        #pragma unroll
        for (int j = 0; j < 8; ++j) {
            unsigned int u = (unsigned int)(unsigned short)r0[j]
                           | ((unsigned int)(unsigned short)r1[j] << 16);
            *(unsigned int*)(dbase + j * pitch) = u;
        }
    }
}

// --------------- fused W-generation + forward transform ----------------------
// bid < 512: wfuse half. bid >= 512: tf2 half -> Z in [b][r][s][o] layout.
__global__ __launch_bounds__(256) void k_wtf(
    const float* __restrict__ fwY, const float* __restrict__ fwX,
    const float* __restrict__ att,
    unsigned short* __restrict__ WrTy, unsigned short* __restrict__ WiTy,
    unsigned short* __restrict__ WinTy,
    unsigned short* __restrict__ WrTx, unsigned short* __restrict__ WiTx,
    unsigned short* __restrict__ WinTx,
    const unsigned short* __restrict__ tabY, const unsigned short* __restrict__ tabX,
    const unsigned short* __restrict__ Hb,
    unsigned short* __restrict__ Zy, unsigned short* __restrict__ Zx)
{
    __shared__ __align__(16) unsigned char smem[34816];  // max(tf2 34816, wfuse 33280)
    int bid = blockIdx.x;
    int tid = threadIdx.x;
    if (bid < 512) {
        // ---- wfuse ----
        int o = bid & 63, b = (bid >> 6) & 3, z = bid >> 8;
        const float* fw = z ? fwX : fwY;
        unsigned short* WrT  = z ? WrTx  : WrTy;
        unsigned short* WiT  = z ? WiTx  : WiTy;
        unsigned short* WinT = z ? WinTx : WinTy;
        float av[4];
        av[0] = att[b * 4 + 0]; av[1] = att[b * 4 + 1];
        av[2] = att[b * 4 + 2]; av[3] = att[b * 4 + 3];
        float acc[32];
        #pragma unroll
        for (int j = 0; j < 32; ++j) acc[j] = 0.0f;
        long toff = (long)(tid >> 7) * 8192 + o * 128 + (tid & 127);
        for (int k = 0; k < 4; ++k) {
            const float* p = fw + (long)k * 524288 + toff;
            float a = av[k];
            #pragma unroll
            for (int j = 0; j < 32; ++j) acc[j] += a * p[j * 16384];
        }
        float* ldsR = (float*)smem;              // 64*65*4 = 16640 B
        float* ldsI = (float*)(smem + 16640);    // +16640 = 33280 B total
        int m = (tid & 127) >> 1, c = tid & 1;
        int ib = tid >> 7;
        #pragma unroll
        for (int j = 0; j < 32; ++j) {
            int i = j * 2 + ib;
            (c ? ldsI : ldsR)[m * 65 + i] = acc[j];
        }
        __syncthreads();
        long ob = (long)b * 262144 + o * 64;   // + m*4096 + i
        #pragma unroll
        for (int it = 0; it < 16; ++it) {
            int idx = it * 256 + tid;
            int mm = idx >> 6, ii = idx & 63;
            float rr = ldsR[mm * 65 + ii], im = ldsI[mm * 65 + ii];
            long a = ob + (long)mm * 4096 + ii;
            WrT[a]  = f2bf(rr);
            WiT[a]  = f2bf(im);
            WinT[a] = f2bf(-im);
        }
        return;
    }
    // ---- tf2 ----
    unsigned short* ldsB = (unsigned short*)smem;   // 64*272*2 = 34816 B
    int g2 = bid - 512;
    int br = g2 >> 10, g = g2 & 1023;
    int b = g >> 8, s = g & 255;
    const unsigned short* tab = br ? tabX : tabY;
    unsigned short* Zo = br ? Zx : Zy;
    long sLo = br ? 64L : 16384L;
    int rowStride = br ? 16384 : 64;
    const unsigned short* src = Hb + (long)b * 4194304 + (long)s * sLo;
    stage_bt(ldsB, 272, src, rowStride, 256, tid);
    __syncthreads();
    int w = tid >> 6, lane = tid & 63, q = lane >> 4, ln = lane & 15;
    f4 acc[2][4];
    #pragma unroll
    for (int mi = 0; mi < 2; ++mi)
        #pragma unroll
        for (int ni = 0; ni < 4; ++ni) acc[mi][ni] = (f4){0.f, 0.f, 0.f, 0.f};
    for (int kc = 0; kc < 256; kc += 32) {
        sh8 a[2], bf[4];
        #pragma unroll
        for (int mi = 0; mi < 2; ++mi)
            a[mi] = *(const sh8*)(tab + (w * 32 + mi * 16 + ln) * 256 + kc + q * 8);
        #pragma unroll
        for (int ni = 0; ni < 4; ++ni)
            bf[ni] = *(const sh8*)(ldsB + (ni * 16 + ln) * 272 + kc + q * 8);
        #pragma unroll
        for (int mi = 0; mi < 2; ++mi)
            #pragma unroll
            for (int ni = 0; ni < 4; ++ni)
                acc[mi][ni] = __builtin_amdgcn_mfma_f32_16x16x32_bf16(
                    a[mi], bf[ni], acc[mi][ni], 0, 0, 0);
    }
    // write Z[b][r][s][o]
    long zB = (long)b * 2097152 + (long)s * 64;
    #pragma unroll
    for (int mi = 0; mi < 2; ++mi)
        #pragma unroll
        for (int ni = 0; ni < 4; ++ni)
            #pragma unroll
            for (int reg = 0; reg < 4; ++reg) {
                int r = w * 32 + mi * 16 + q * 4 + reg;
                Zo[zB + (long)r * 16384 + ni * 16 + ln] = f2bf(acc[mi][ni][reg]);
            }
}

// ------------------------- MFMA complex mode-mix, both branches --------------
// Z layout [b][r][s][o]: freq rows 2m (Re) / 2m+1 (Im) are 16384-sh planes;
// lane stride along s is 64 sh (128 B) -> fully-coalesced reads and writes.
__global__ __launch_bounds__(256) void k_mixm2(
    unsigned short* Zy, unsigned short* Zx,
    const unsigned short* __restrict__ WrTy, const unsigned short* __restrict__ WiTy,
    const unsigned short* __restrict__ WinTy,
    const unsigned short* __restrict__ WrTx, const unsigned short* __restrict__ WiTx,
    const unsigned short* __restrict__ WinTx)
{
    int xt = blockIdx.x, g = blockIdx.y, z = blockIdx.z;
    unsigned short* Z = z ? Zx : Zy;
    const unsigned short* WrT  = z ? WrTx  : WrTy;
    const unsigned short* WiT  = z ? WiTx  : WiTy;
    const unsigned short* WinT = z ? WinTx : WinTy;
    int b = g >> 6, m = g & 63;
    int tid = threadIdx.x, w = tid >> 6, lane = tid & 63, q = lane >> 4, ln = lane & 15;
    long zBr = (long)b * 2097152 + (long)(2 * m) * 16384;   // Re plane; Im at +16384
    long wB = (long)b * 262144 + (long)m * 4096;
    int s0 = xt * 64 + w * 16;
    f4 aR[4], aI[4];
    #pragma unroll
    for (int nt = 0; nt < 4; ++nt) { aR[nt] = (f4){0.f,0.f,0.f,0.f}; aI[nt] = (f4){0.f,0.f,0.f,0.f}; }
    for (int kc = 0; kc < 64; kc += 32) {
        sh8 zr = *(const sh8*)(Z + zBr + (long)(s0 + ln) * 64 + kc + q * 8);
        sh8 zi = *(const sh8*)(Z + zBr + 16384 + (long)(s0 + ln) * 64 + kc + q * 8);
        #pragma unroll
        for (int nt = 0; nt < 4; ++nt) {
            int o = nt * 16 + ln;
            sh8 wr = *(const sh8*)(WrT + wB + o * 64 + kc + q * 8);
            sh8 wi = *(const sh8*)(WiT + wB + o * 64 + kc + q * 8);
            sh8 wn = *(const sh8*)(WinT + wB + o * 64 + kc + q * 8);
            aR[nt] = __builtin_amdgcn_mfma_f32_16x16x32_bf16(zr, wr, aR[nt], 0, 0, 0);
            aR[nt] = __builtin_amdgcn_mfma_f32_16x16x32_bf16(zi, wn, aR[nt], 0, 0, 0);
            aI[nt] = __builtin_amdgcn_mfma_f32_16x16x32_bf16(zr, wi, aI[nt], 0, 0, 0);
            aI[nt] = __builtin_amdgcn_mfma_f32_16x16x32_bf16(zi, wr, aI[nt], 0, 0, 0);
        }
    }
    #pragma unroll
    for (int nt = 0; nt < 4; ++nt)
        #pragma unroll
        for (int reg = 0; reg < 4; ++reg) {
            int s = s0 + q * 4 + reg;
            long a = zBr + (long)s * 64 + nt * 16 + ln;
            Z[a]          = f2bf(aR[nt][reg]);
            Z[a + 16384]  = f2bf(aI[nt][reg]);
        }
}

// ------------------------- MFMA inverse transform, both branches -------------
// Z layout [b][r][s][o]: stage with rowStride 16384 at base +s*64.
// BOTH branches write R in [b][x][y][o] layout:
//   z=0 (Ry): s = x, rows r2 = y -> addr = b*4M + s*16384 + r2*64 + o
//   z=1 (Rx): s = y, rows r2 = x -> addr = b*4M + r2*16384 + s*64 + o
__global__ __launch_bounds__(256) void k_ti2(
    const unsigned short* __restrict__ tabY, const unsigned short* __restrict__ tabX,
    const unsigned short* __restrict__ Zy, const unsigned short* __restrict__ Zx,
    unsigned short* __restrict__ Ry, unsigned short* __restrict__ Rx)
{
    __shared__ __align__(16) unsigned short ldsB[64 * 144];
    int g = blockIdx.x, br = blockIdx.y;
    int b = g >> 8, s = g & 255;
    const unsigned short* tab = br ? tabX : tabY;
    const unsigned short* Zl  = br ? Zx : Zy;
    unsigned short* Ro = br ? Rx : Ry;
    int tid = threadIdx.x;
    const unsigned short* src = Zl + (long)b * 2097152 + (long)s * 64;
    stage_bt(ldsB, 144, src, 16384, 128, tid);
    __syncthreads();
    int w = tid >> 6, lane = tid & 63, q = lane >> 4, ln = lane & 15;
    f4 acc[4][4];
    #pragma unroll
    for (int mi = 0; mi < 4; ++mi)
        #pragma unroll
        for (int ni = 0; ni < 4; ++ni) acc[mi][ni] = (f4){0.f, 0.f, 0.f, 0.f};
    for (int kc = 0; kc < 128; kc += 32) {
        sh8 a[4], bf[4];
        #pragma unroll
        for (int mi = 0; mi < 4; ++mi)
            a[mi] = *(const sh8*)(tab + (w * 64 + mi * 16 + ln) * 128 + kc + q * 8);
        #pragma unroll
        for (int ni = 0; ni < 4; ++ni)
            bf[ni] = *(const sh8*)(ldsB + (ni * 16 + ln) * 144 + kc + q * 8);
        #pragma unroll
        for (int mi = 0; mi < 4; ++mi)
            #pragma unroll
            for (int ni = 0; ni < 4; ++ni)
                acc[mi][ni] = __builtin_amdgcn_mfma_f32_16x16x32_bf16(
                    a[mi], bf[ni], acc[mi][ni], 0, 0, 0);
    }
    long rB0 = (long)b * 4194304;
    #pragma unroll
    for (int mi = 0; mi < 4; ++mi)
        #pragma unroll
        for (int ni = 0; ni < 4; ++ni)
            #pragma unroll
            for (int reg = 0; reg < 4; ++reg) {
                int r2 = w * 64 + mi * 16 + q * 4 + reg;
                long a;
                if (br) a = rB0 + (long)r2 * 16384 + (long)s * 64 + ni * 16 + ln;
                else    a = rB0 + (long)s * 16384 + (long)r2 * 64 + ni * 16 + ln;
                Ro[a] = f2bf(acc[mi][ni][reg]);
            }
}

// ------------------------- MFMA fused FeedForward + LN -----------------------
// A = bf16(Ry + Rx) built in registers; residual stream in bf16 (Hb).
// R11: 1024 blocks x 4 row-tiles with register prefetch of next tile's
//      Ry/Rx -> loads in flight across the current tile's MFMA chain.
//      T rows stay wave-private (intra-wave dep only, no barriers).
__global__ __launch_bounds__(256) void k_ffm(
    const unsigned short* __restrict__ Ry, const unsigned short* __restrict__ Rx,
    const unsigned short* __restrict__ W0T, const float* __restrict__ b0,
    const unsigned short* __restrict__ W1T, const float* __restrict__ b1,
    const float* __restrict__ g1, const float* __restrict__ be1,
    unsigned short* __restrict__ Hb, int last)
{
    __shared__ __align__(16) unsigned short T[64 * 264];
    int tid = threadIdx.x, w = tid >> 6, lane = tid & 63, q = lane >> 4, ln = lane & 15;
    int base0 = blockIdx.x * 256;        // 4 tiles of 64 rows
    // preload tile 0
    sh8 ryc[2], rxc[2];
    {
        long r0 = (long)(base0 + w * 16 + ln) * 64;
        ryc[0] = *(const sh8*)(Ry + r0 + q * 8);
        ryc[1] = *(const sh8*)(Ry + r0 + 32 + q * 8);
        rxc[0] = *(const sh8*)(Rx + r0 + q * 8);
        rxc[1] = *(const sh8*)(Rx + r0 + 32 + q * 8);
    }
    for (int it = 0; it < 4; ++it) {
        int m0 = base0 + it * 64;
        // prefetch tile it+1 (stays in flight across this tile's compute)
        sh8 ryn[2], rxn[2];
        if (it < 3) {
            long rn = (long)(m0 + 64 + w * 16 + ln) * 64;
            ryn[0] = *(const sh8*)(Ry + rn + q * 8);
            ryn[1] = *(const sh8*)(Ry + rn + 32 + q * 8);
            rxn[0] = *(const sh8*)(Rx + rn + q * 8);
            rxn[1] = *(const sh8*)(Rx + rn + 32 + q * 8);
        }
        // phase 1: T = relu((Ry+Rx) @ W0 + b0), wave rows w*16..+15, N=256
        {
            f4 acc1[16];
            #pragma unroll
            for (int nt = 0; nt < 16; ++nt) acc1[nt] = (f4){0.f, 0.f, 0.f, 0.f};
            #pragma unroll
            for (int kc2 = 0; kc2 < 2; ++kc2) {
                sh8 a;
                #pragma unroll
                for (int j = 0; j < 8; ++j)
                    a[j] = (short)f2bf(bf2f((unsigned short)ryc[kc2][j])
                                     + bf2f((unsigned short)rxc[kc2][j]));
                #pragma unroll
                for (int nt = 0; nt < 16; ++nt) {
                    sh8 bf = *(const sh8*)(W0T + (nt * 16 + ln) * 64 + kc2 * 32 + q * 8);
                    acc1[nt] = __builtin_amdgcn_mfma_f32_16x16x32_bf16(a, bf, acc1[nt], 0, 0, 0);
                }
            }
            #pragma unroll
            for (int nt = 0; nt < 16; ++nt) {
                int n = nt * 16 + ln;
                float bias = b0[n];
                #pragma unroll
                for (int reg = 0; reg < 4; ++reg) {
                    int m = w * 16 + q * 4 + reg;
                    T[m * 264 + n] = f2bf(fmaxf(acc1[nt][reg] + bias, 0.0f));
                }
            }
        }
        // residual loads for this tile (covered by phase 2's MFMA chain)
        float hbold[16];
        if (!last) {
            #pragma unroll
            for (int reg = 0; reg < 4; ++reg)
                #pragma unroll
                for (int nt = 0; nt < 4; ++nt)
                    hbold[reg * 4 + nt] =
                        bf2f(Hb[(long)(m0 + w * 16 + q * 4 + reg) * 64 + nt * 16 + ln]);
        }
        // phase 2 (intra-wave LDS dep): t = T @ W1 + b1, then LN + residual
        f4 acc2[4];
        #pragma unroll
        for (int nt = 0; nt < 4; ++nt) acc2[nt] = (f4){0.f, 0.f, 0.f, 0.f};
        for (int kc = 0; kc < 256; kc += 32) {
            sh8 a = *(const sh8*)(T + (w * 16 + ln) * 264 + kc + q * 8);
            #pragma unroll
            for (int nt = 0; nt < 4; ++nt) {
                sh8 bf = *(const sh8*)(W1T + (nt * 16 + ln) * 256 + kc + q * 8);
                acc2[nt] = __builtin_amdgcn_mfma_f32_16x16x32_bf16(a, bf, acc2[nt], 0, 0, 0);
            }
        }
        float bia[4], gg[4], bb4[4];
        #pragma unroll
        for (int nt = 0; nt < 4; ++nt) {
            int n = nt * 16 + ln;
            bia[nt] = b1[n]; gg[nt] = g1[n]; bb4[nt] = be1[n];
        }
        #pragma unroll
        for (int reg = 0; reg < 4; ++reg) {
            float t[4];
            float s = 0.f, qs = 0.f;
            #pragma unroll
            for (int nt = 0; nt < 4; ++nt) {
                t[nt] = acc2[nt][reg] + bia[nt];
                s += t[nt]; qs += t[nt] * t[nt];
            }
            #pragma unroll
            for (int d = 1; d < 16; d <<= 1) {
                s  += __shfl_xor(s, d, 64);
                qs += __shfl_xor(qs, d, 64);
            }
            float mean = s * (1.0f / 64.0f);
            float var  = qs * (1.0f / 64.0f) - mean * mean;
            float inv  = rsqrtf(var + 1e-5f);
            int m = w * 16 + q * 4 + reg;
            long base = (long)(m0 + m) * 64;
            #pragma unroll
            for (int nt = 0; nt < 4; ++nt) {
                int n = nt * 16 + ln;
                float v = (t[nt] - mean) * inv * gg[nt] + bb4[nt];
                float hv;
                if (last) hv = gelu_fast(v);
                else      hv = hbold[reg * 4 + nt] + v;
                Hb[base + n] = f2bf(hv);
            }
        }
        // rotate prefetched tile into current (only when a prefetch happened)
        if (it < 3) {
            ryc[0] = ryn[0]; ryc[1] = ryn[1];
            rxc[0] = rxn[0]; rxc[1] = rxn[1];
        }
    }
}

// ------------------------- output heads (MFMA ha + fp32 conv) ----------------
// px-quarter per dispatch (pxQ): dim3(256,5) x 4 launches. Same math as R4.
__global__ __launch_bounds__(256) void k_headm(
    const unsigned short* __restrict__ Hb, const float* __restrict__ x0,
    const unsigned short* __restrict__ Wcat, const float* __restrict__ bcat,
    const float* __restrict__ c1w, const float* __restrict__ c1b,
    const float* __restrict__ c2w, const float* __restrict__ c2b,
    float* __restrict__ out, int pxQ)
{
    __shared__ unsigned short ha[256 * 74];   // [px][j], pitch 74 (gcd(37,32)=1)
    int tid = threadIdx.x;
    int f = blockIdx.y;
    long px0 = (long)(pxQ * 256 + blockIdx.x) * 256;
    int w = tid >> 6, lane = tid & 63, q = lane >> 4, ln = lane & 15;

    // ha-GEMM, one mi (16 rows) at a time: acc[5] live, not acc[4][5]
    #pragma unroll
    for (int mi = 0; mi < 4; ++mi) {
        f4 acc[5];
        #pragma unroll
        for (int nt = 0; nt < 5; ++nt) acc[nt] = (f4){0.f, 0.f, 0.f, 0.f};
        #pragma unroll
        for (int kc = 0; kc < 2; ++kc) {
            sh8 a = *(const sh8*)(Hb + (px0 + w * 64 + mi * 16 + ln) * 64
                                   + kc * 32 + q * 8);
            #pragma unroll
            for (int nt = 0; nt < 5; ++nt) {
                sh8 bf = *(const sh8*)(Wcat + f * 5120 + (nt * 16 + ln) * 64
                                        + kc * 32 + q * 8);
                acc[nt] = __builtin_amdgcn_mfma_f32_16x16x32_bf16(a, bf, acc[nt], 0, 0, 0);
            }
        }
        #pragma unroll
        for (int nt = 0; nt < 5; ++nt) {
            int n = nt * 16 + ln;
            if (n < 70) {
                float bias = bcat[f * 80 + n];
                #pragma unroll
                for (int reg = 0; reg < 4; ++reg) {
                    int m = w * 64 + mi * 16 + q * 4 + reg;
                    ha[m * 74 + n] = f2bf(gelu_fast(acc[nt][reg] + bias));
                }
            }
        }
    }
    __syncthreads();

    // conv phase: one pixel per thread, fp32 FMA.
    float u2[10];
    float b2v = c2b[f];
    #pragma unroll
    for (int d = 0; d < 10; ++d) u2[d] = b2v;
    #pragma unroll
    for (int h = 0; h < 2; ++h) {
        float hw[40];   // hv[30h .. 30h+39]
        #pragma unroll
        for (int i = 0; i < 20; ++i) {
            unsigned int u = *(const unsigned int*)(ha + tid * 74 + h * 30 + 2 * i);
            hw[2 * i]     = __uint_as_float(u << 16);
            hw[2 * i + 1] = __uint_as_float(u & 0xffff0000u);
        }
        #pragma unroll 1
        for (int c = 0; c < 8; ++c) {
            int fc = f * 8 + c;
            float w1r[12], w2r[12];   // wave-uniform -> SGPRs
            #pragma unroll
            for (int j = 0; j < 12; ++j) {
                w1r[j] = c1w[fc * 12 + j];
                w2r[j] = c2w[fc * 12 + j];
            }
            float bc = c1b[fc];
            #pragma unroll
            for (int pl = 0; pl < 15; ++pl) {
                const int p = h * 15 + pl;     // compile-time after unroll
                float s = bc;
                #pragma unroll
                for (int j = 0; j < 12; ++j)
                    s = fmaf(hw[2 * pl + j], w1r[j], s);
                float g = gelu_fast(s);
                #pragma unroll
                for (int d = 0; d < 10; ++d) {
                    const int j2 = p - 2 * d;  // compile-time bounds
                    if (j2 >= 0 && j2 < 12)
                        u2[d] = fmaf(g, w2r[j2], u2[d]);
                }
            }
        }
    }
    long px = px0 + tid;
    float xv = x0[px * 5 + f];
    #pragma unroll
    for (int d = 0; d < 10; ++d)
        out[px * 50 + f * 10 + d] = xv + u2[d] * (float)(d + 1) * 0.1f;
}

// ---------------------------------------------------------------------------
extern "C" void kernel_launch(void* const* d_in, const int* in_sizes, int n_in,
                              void* d_out, int out_size, void* d_ws, size_t ws_size,
                              hipStream_t stream) {
    (void)in_sizes; (void)n_in; (void)out_size; (void)ws_size;
    const float* xin    = (const float*)d_in[0];
    const float* params = (const float*)d_in[1];
    const float* in_w   = (const float*)d_in[2];
    const float* in_b   = (const float*)d_in[3];
    const float* fnu_w1 = (const float*)d_in[4];
    const float* fnu_b1 = (const float*)d_in[5];
    const float* fnu_w2 = (const float*)d_in[6];
    const float* fnu_b2 = (const float*)d_in[7];
    const float* fnu_w3 = (const float*)d_in[8];
    const float* fnu_b3 = (const float*)d_in[9];
    const float* fw_y   = (const float*)d_in[10];
    const float* fw_x   = (const float*)d_in[11];
    const float* ff_w0  = (const float*)d_in[12];
    const float* ff_b0  = (const float*)d_in[13];
    const float* ff_w1  = (const float*)d_in[14];
    const float* ff_b1  = (const float*)d_in[15];
    const float* ln_g   = (const float*)d_in[16];
    const float* ln_b   = (const float*)d_in[17];
    const float* fa_w   = (const float*)d_in[18];
    const float* fa_b   = (const float*)d_in[19];
    const float* fb_w   = (const float*)d_in[20];
    const float* fb_b   = (const float*)d_in[21];
    const float* c1_w   = (const float*)d_in[22];
    const float* c1_b   = (const float*)d_in[23];
    const float* c2_w   = (const float*)d_in[24];
    const float* c2_b   = (const float*)d_in[25];
    float* out = (float*)d_out;
    float* ws  = (float*)d_ws;

    // workspace (float offsets), total ~41.0M floats (~164 MB)
    unsigned short* tabBf = (unsigned short*)(ws + 0);        // 131072 sh
    unsigned short* tabYF = tabBf;
    unsigned short* tabXF = tabBf + 32768;
    unsigned short* tabYI = tabBf + 65536;
    unsigned short* tabXI = tabBf + 98304;
    unsigned short* W0T   = (unsigned short*)(ws + 65536);    // 65536 sh
    unsigned short* W1T   = (unsigned short*)(ws + 98304);    // 65536 sh
    unsigned short* Wcat  = (unsigned short*)(ws + 131072);   // 25600 sh
    float* bcat = ws + 143872;                                 // 400
    float* att  = ws + 144272;                                 // 64
    unsigned int* c1p = (unsigned int*)(ws + 144336);          // 240 (layout compat)
    unsigned int* c2p = (unsigned int*)(ws + 144576);          // 240 (layout compat)
    unsigned short* Hbf = (unsigned short*)(ws + 144816);      // 16.8M sh
    // WRy..WIx fp32 slots (ws+8533424..) unused since R5 (wfuse writes bf16 direct)
    unsigned short* WrTy  = (unsigned short*)(ws + 12727728);  // 1M sh each
    unsigned short* WiTy  = (unsigned short*)(ws + 13252016);
    unsigned short* WinTy = (unsigned short*)(ws + 13776304);
    unsigned short* WrTx  = (unsigned short*)(ws + 14300592);
    unsigned short* WiTx  = (unsigned short*)(ws + 14824880);
    unsigned short* WinTx = (unsigned short*)(ws + 15349168);
    unsigned short* Zy    = (unsigned short*)(ws + 15873456);  // 8.4M sh
    unsigned short* Zx    = (unsigned short*)(ws + 20067760);  // 8.4M sh
    unsigned short* Ry    = (unsigned short*)(ws + 24262064);  // 16.8M sh
    unsigned short* Rx    = (unsigned short*)(ws + 32650672);  // 16.8M sh

    // fused front: prep + att + embed (independent) in one dispatch
    k_front<<<17513, 256, 0, stream>>>(
        ff_w0, ff_w1, fa_w, fb_w, fa_b, fb_b, c1_w, c2_w,
        tabBf, W0T, W1T, Wcat, bcat, c1p, c2p,
        params, fnu_w1, fnu_b1, fnu_w2, fnu_b2, fnu_w3, fnu_b3, att,
        xin, in_w, in_b, Hbf);

    for (int lay = 0; lay < 4; ++lay) {
        const float* attL = att + lay * 16;
        // fused W-gen + forward transform (independent halves)
        k_wtf<<<2560, 256, 0, stream>>>(
            fw_y + (long)lay * 2097152, fw_x + (long)lay * 2097152, attL,
            WrTy, WiTy, WinTy, WrTx, WiTx, WinTx,
            tabYF, tabXF, Hbf, Zy, Zx);
        k_mixm2<<<dim3(4, 256, 2), 256, 0, stream>>>(
            Zy, Zx, WrTy, WiTy, WinTy, WrTx, WiTx, WinTx);
        k_ti2<<<dim3(1024, 2), 256, 0, stream>>>(tabYI, tabXI, Zy, Zx, Ry, Rx);
        k_ffm<<<1024, 256, 0, stream>>>(
            Ry, Rx, W0T + lay * 16384, ff_b0 + lay * 256,
            W1T + lay * 16384, ff_b1 + lay * 64,
            ln_g + lay * 64, ln_b + lay * 64,
            Hbf, (lay == 3) ? 1 : 0);
    }
    // k_headm split into 4 px-quarters (~65us each): keeps layer kernels
    // visible in the top-5 dispatch table with full counters.
    for (int pq = 0; pq < 4; ++pq)
        k_headm<<<dim3(256, 5), 256, 0, stream>>>(Hbf, xin, Wcat, bcat,
                                                  c1_w, c1_b, c2_w, c2_b, out, pq);
}

// Round 13
// 1239.804 us; speedup vs baseline: 1.3164x; 1.0682x over previous
//
#include <hip/hip_runtime.h>
#include <math.h>

// ---------------------------------------------------------------------------
// OmniFluids2D forward on MI355X. bf16 dataflow + MFMA everywhere GEMM-shaped.
// Y/X spectral branches merged into double-width launches. B=4, 256^2, W=64.
// R13: k_front's serial attention block was the kernel's critical path
//     (~100us on ONE block: 16 (lay,b) combos x serial 128-iter dep chains).
//     Now 16 att blocks (one per (lay,b)), thread-parallel dot products with
//     4-way partial sums + shuffle/LDS logit reduction. Prep/embed bids shift.
// ---------------------------------------------------------------------------

typedef __attribute__((ext_vector_type(8))) short sh8;
typedef __attribute__((ext_vector_type(4))) float f4;

__device__ __forceinline__ float fast_rcp(float x) {
#if defined(__has_builtin)
#if __has_builtin(__builtin_amdgcn_rcpf)
    return __builtin_amdgcn_rcpf(x);
#else
    return 1.0f / x;
#endif
#else
    return 1.0f / x;
#endif
}

__device__ __forceinline__ float gelu_f(float v) {          // exact (att only)
    return 0.5f * v * (1.0f + erff(v * 0.70710678118654752f));
}
__device__ __forceinline__ float gelu_fast(float v) {       // tanh-approx, rcp
    float s = v * (1.5957691216f + 0.0713548162f * v * v);
    float e = __expf(-s);
    return v * fast_rcp(1.0f + e);
}
__device__ __forceinline__ unsigned short f2bf(float x) {
    unsigned int u = __float_as_uint(x);
    u += 0x7fffu + ((u >> 16) & 1u);
    return (unsigned short)(u >> 16);
}
__device__ __forceinline__ float bf2f(unsigned short h) {
    return __uint_as_float(((unsigned int)h) << 16);
}

// --------------- fused front: att (16 blocks) + prep + embed -----------------
// bid 0..15: routing attention for (lay=bid>>2, b=bid&3), thread-parallel.
// bid 16..1143: prep. bid 1144+: embed.
__global__ __launch_bounds__(256) void k_front(
    const float* __restrict__ ff_w0, const float* __restrict__ ff_w1,
    const float* __restrict__ fa_w, const float* __restrict__ fb_w,
    const float* __restrict__ fa_b, const float* __restrict__ fb_b,
    const float* __restrict__ c1w, const float* __restrict__ c2w,
    unsigned short* __restrict__ tabBf,
    unsigned short* __restrict__ W0T, unsigned short* __restrict__ W1T,
    unsigned short* __restrict__ Wcat, float* __restrict__ bcat,
    unsigned int* __restrict__ c1p, unsigned int* __restrict__ c2p,
    const float* __restrict__ params,
    const float* __restrict__ w1, const float* __restrict__ b1,
    const float* __restrict__ w2, const float* __restrict__ b2,
    const float* __restrict__ w3, const float* __restrict__ b3,
    float* __restrict__ att,
    const float* __restrict__ xin,
    const float* __restrict__ inw, const float* __restrict__ inb,
    unsigned short* __restrict__ Hb)
{
    int bid = blockIdx.x;
    int tid = threadIdx.x;
    if (bid < 16) {
        // ---- routing attention for one (lay, b); 128 active threads ----
        int lay = bid >> 2, b = bid & 3;
        __shared__ float A1[128], LG2[8];
        float A2v = 0.0f;
        int j = tid;
        if (j < 128) {
            float s = b1[lay * 128 + j];
            #pragma unroll
            for (int p = 0; p < 8; ++p)
                s += params[b * 8 + p] * w1[(lay * 8 + p) * 128 + j];
            A1[j] = gelu_f(s);
        }
        __syncthreads();
        if (j < 128) {
            float s0 = 0.f, s1 = 0.f, s2 = 0.f, s3 = 0.f;
            for (int q = 0; q < 128; q += 4) {
                s0 += A1[q]     * w2[(lay * 128 + q)     * 128 + j];
                s1 += A1[q + 1] * w2[(lay * 128 + q + 1) * 128 + j];
                s2 += A1[q + 2] * w2[(lay * 128 + q + 2) * 128 + j];
                s3 += A1[q + 3] * w2[(lay * 128 + q + 3) * 128 + j];
            }
            A2v = gelu_f(b2[lay * 128 + j] + ((s0 + s1) + (s2 + s3)));
        }
        // logits: per-thread products, wave shuffle reduce, cross-wave via LDS
        float p[4];
        #pragma unroll
        for (int t = 0; t < 4; ++t)
            p[t] = (j < 128) ? A2v * w3[(lay * 128 + j) * 4 + t] : 0.0f;
        #pragma unroll
        for (int t = 0; t < 4; ++t)
            #pragma unroll
            for (int d = 1; d < 64; d <<= 1)
                p[t] += __shfl_xor(p[t], d, 64);
        if ((tid & 63) == 0 && tid < 128) {
            int wv = tid >> 6;   // 0 or 1
            #pragma unroll
            for (int t = 0; t < 4; ++t) LG2[wv * 4 + t] = p[t];
        }
        __syncthreads();
        if (tid == 0) {
            float lg[4];
            #pragma unroll
            for (int t = 0; t < 4; ++t)
                lg[t] = (LG2[t] + LG2[4 + t] + b3[lay * 4 + t]) * 0.1f;
            float mx = fmaxf(fmaxf(lg[0], lg[1]), fmaxf(lg[2], lg[3]));
            float e0 = expf(lg[0] - mx), e1 = expf(lg[1] - mx);
            float e2 = expf(lg[2] - mx), e3 = expf(lg[3] - mx);
            float inv = 1.0f / (e0 + e1 + e2 + e3);
            att[lay * 16 + b * 4 + 0] = e0 * inv;
            att[lay * 16 + b * 4 + 1] = e1 * inv;
            att[lay * 16 + b * 4 + 2] = e2 * inv;
            att[lay * 16 + b * 4 + 3] = e3 * inv;
        }
        return;
    }
    if (bid <= 1143) {
        // ---- prep: trig tables + weight packing ----
        int idx = (bid - 16) * 256 + tid;
        if (idx < 131072) {
            int t = idx >> 15, r = idx & 32767;
            const double PI = 3.14159265358979323846;
            const double s510 = 1.0 / sqrt(510.0);
            double v = 0.0;
            if (t == 0) {            // TAB_YF [row=2m+c][y]  (128x256)
                int row = r >> 8, y = r & 255;
                int m = row >> 1, c = row & 1;
                double ang = 2.0 * PI * (double)(m * y) / 256.0;
                v = (c == 0 ? cos(ang) : -sin(ang)) / 16.0;
            } else if (t == 1) {     // TAB_XF [row=2k+c][x]  (128x256)
                int row = r >> 8, xx = r & 255;
                int k = row >> 1, c = row & 1;
                if (c == 0) {
                    v = 0.0;
                    if (xx == 0)   v = s510;
                    if (xx == 255) v = (k & 1) ? -s510 : s510;
                } else {
                    double ang = PI * (double)(k * xx) / 255.0;
                    v = -2.0 * s510 * sin(ang);
                }
            } else if (t == 2) {     // TAB_YI [y][row=2m+c]  (256x128)
                int y = r >> 7, row = r & 127;
                int m = row >> 1, c = row & 1;
                double ang = 2.0 * PI * (double)(m * y) / 256.0;
                if (c == 0) v = (m == 0 ? 1.0 : 2.0 * cos(ang)) / 16.0;
                else        v = (m == 0 ? 0.0 : -2.0 * sin(ang) / 16.0);
            } else {                 // TAB_XI [x][row=2k+c]  (256x128)
                int xx = r >> 7, row = r & 127;
                int k = row >> 1, c = row & 1;
                double ang = PI * (double)(k * xx) / 255.0;
                if (c == 0) v = s510 * (k == 0 ? 1.0 : 2.0 * cos(ang));
                else        v = (k == 0 ? 0.0 : -2.0 * s510 * sin(ang));
            }
            tabBf[idx] = f2bf((float)v);
            return;
        }
        idx -= 131072;
        if (idx < 65536) {
            int l = idx >> 14, rem = idx & 16383;
            int n = rem >> 6, k = rem & 63;
            W0T[idx] = f2bf(ff_w0[l * 16384 + k * 256 + n]);
        } else if (idx < 131072) {
            int j = idx - 65536;
            int l = j >> 14, rem = j & 16383;
            int n = rem >> 8, k = rem & 255;
            W1T[j] = f2bf(ff_w1[l * 16384 + k * 64 + n]);
        } else if (idx < 156672) {
            int j = idx - 131072;
            int f = j / 5120, r2 = j % 5120;
            int n = r2 >> 6, k = r2 & 63;
            float v = 0.0f;
            if (n < 36)      v = fa_w[f * 2304 + k * 36 + n];
            else if (n < 70) v = fb_w[f * 2176 + k * 34 + (n - 36)];
            Wcat[j] = f2bf(v);
        } else if (idx < 157072) {
            int j = idx - 156672;
            int f = j / 80, n = j % 80;
            float v = 0.0f;
            if (n < 36)      v = fa_b[f * 36 + n];
            else if (n < 70) v = fb_b[f * 34 + (n - 36)];
            bcat[j] = v;
        } else if (idx < 157552) {
            int j = idx - 157072;         // 0..479 (workspace layout compat)
            int half = j >= 240;
            int r = j - half * 240;
            int fc = r / 6, jj = r % 6;
            const float* src = half ? c2w : c1w;
            unsigned int u = (unsigned int)f2bf(src[fc * 12 + 2 * jj])
                           | ((unsigned int)f2bf(src[fc * 12 + 2 * jj + 1]) << 16);
            (half ? c2p : c1p)[r] = u;
        }
        return;
    }
    // ---- input embedding ----
    {
        long gid = (long)(bid - 1144) * 256 + tid;   // 0..4194303
        long px = gid >> 4;
        int c4 = (int)(gid & 15) * 4;
        int y = (int)(px & 255), xi = (int)((px >> 8) & 255);
        const float* xp = xin + px * 5;
        float v[7];
        v[0] = xp[0]; v[1] = xp[1]; v[2] = xp[2]; v[3] = xp[3]; v[4] = xp[4];
        const float STEP = 6.283185307179586f / 256.0f;
        v[5] = xi * STEP;
        v[6] = y * STEP;
        float r[4];
        #pragma unroll
        for (int c = 0; c < 4; ++c) {
            int ch = c4 + c;
            float s = inb[ch];
            #pragma unroll
            for (int p = 0; p < 7; ++p) s += v[p] * inw[p * 64 + ch];
            r[c] = gelu_fast(s);
        }
        uint2 uu;
        uu.x = (unsigned int)f2bf(r[0]) | ((unsigned int)f2bf(r[1]) << 16);
        uu.y = (unsigned int)f2bf(r[2]) | ((unsigned int)f2bf(r[3]) << 16);
        *(uint2*)(Hb + px * 64 + c4) = uu;
    }
}

// ------------------------- B^T staging: global rows -> lds[n][k] -------------
__device__ __forceinline__ void stage_bt(unsigned short* lds, int pitch,
    const unsigned short* src, int rowStride, int K, int tid)
{
    int pairs = K >> 1;
    int tasks = pairs * 8;
    for (int idx = tid; idx < tasks; idx += 256) {
        int p = idx & (pairs - 1);
        int cg = idx / pairs;
        const unsigned short* s0 = src + (long)(2 * p) * rowStride + cg * 8;
        sh8 r0 = *(const sh8*)s0;
        sh8 r1 = *(const sh8*)(s0 + rowStride);
        unsigned short* dbase = lds + cg * 8 * pitch + 2 * p;
        #pragma unroll
        for (int j = 0; j < 8; ++j) {
            unsigned int u = (unsigned int)(unsigned short)r0[j]
                           | ((unsigned int)(unsigned short)r1[j] << 16);
            *(unsigned int*)(dbase + j * pitch) = u;
        }
    }
}

// --------------- fused W-generation + forward transform ----------------------
// bid < 512: wfuse half. bid >= 512: tf2 half -> Z in [b][r][s][o] layout.
__global__ __launch_bounds__(256) void k_wtf(
    const float* __restrict__ fwY, const float* __restrict__ fwX,
    const float* __restrict__ att,
    unsigned short* __restrict__ WrTy, unsigned short* __restrict__ WiTy,
    unsigned short* __restrict__ WinTy,
    unsigned short* __restrict__ WrTx, unsigned short* __restrict__ WiTx,
    unsigned short* __restrict__ WinTx,
    const unsigned short* __restrict__ tabY, const unsigned short* __restrict__ tabX,
    const unsigned short* __restrict__ Hb,
    unsigned short* __restrict__ Zy, unsigned short* __restrict__ Zx)
{
    __shared__ __align__(16) unsigned char smem[34816];  // max(tf2 34816, wfuse 33280)
    int bid = blockIdx.x;
    int tid = threadIdx.x;
    if (bid < 512) {
        // ---- wfuse ----
        int o = bid & 63, b = (bid >> 6) & 3, z = bid >> 8;
        const float* fw = z ? fwX : fwY;
        unsigned short* WrT  = z ? WrTx  : WrTy;
        unsigned short* WiT  = z ? WiTx  : WiTy;
        unsigned short* WinT = z ? WinTx : WinTy;
        float av[4];
        av[0] = att[b * 4 + 0]; av[1] = att[b * 4 + 1];
        av[2] = att[b * 4 + 2]; av[3] = att[b * 4 + 3];
        float acc[32];
        #pragma unroll
        for (int j = 0; j < 32; ++j) acc[j] = 0.0f;
        long toff = (long)(tid >> 7) * 8192 + o * 128 + (tid & 127);
        for (int k = 0; k < 4; ++k) {
            const float* p = fw + (long)k * 524288 + toff;
            float a = av[k];
            #pragma unroll
            for (int j = 0; j < 32; ++j) acc[j] += a * p[j * 16384];
        }
        float* ldsR = (float*)smem;              // 64*65*4 = 16640 B
        float* ldsI = (float*)(smem + 16640);    // +16640 = 33280 B total
        int m = (tid & 127) >> 1, c = tid & 1;
        int ib = tid >> 7;
        #pragma unroll
        for (int j = 0; j < 32; ++j) {
            int i = j * 2 + ib;
            (c ? ldsI : ldsR)[m * 65 + i] = acc[j];
        }
        __syncthreads();
        long ob = (long)b * 262144 + o * 64;   // + m*4096 + i
        #pragma unroll
        for (int it = 0; it < 16; ++it) {
            int idx = it * 256 + tid;
            int mm = idx >> 6, ii = idx & 63;
            float rr = ldsR[mm * 65 + ii], im = ldsI[mm * 65 + ii];
            long a = ob + (long)mm * 4096 + ii;
            WrT[a]  = f2bf(rr);
            WiT[a]  = f2bf(im);
            WinT[a] = f2bf(-im);
        }
        return;
    }
    // ---- tf2 ----
    unsigned short* ldsB = (unsigned short*)smem;   // 64*272*2 = 34816 B
    int g2 = bid - 512;
    int br = g2 >> 10, g = g2 & 1023;
    int b = g >> 8, s = g & 255;
    const unsigned short* tab = br ? tabX : tabY;
    unsigned short* Zo = br ? Zx : Zy;
    long sLo = br ? 64L : 16384L;
    int rowStride = br ? 16384 : 64;
    const unsigned short* src = Hb + (long)b * 4194304 + (long)s * sLo;
    stage_bt(ldsB, 272, src, rowStride, 256, tid);
    __syncthreads();
    int w = tid >> 6, lane = tid & 63, q = lane >> 4, ln = lane & 15;
    f4 acc[2][4];
    #pragma unroll
    for (int mi = 0; mi < 2; ++mi)
        #pragma unroll
        for (int ni = 0; ni < 4; ++ni) acc[mi][ni] = (f4){0.f, 0.f, 0.f, 0.f};
    for (int kc = 0; kc < 256; kc += 32) {
        sh8 a[2], bf[4];
        #pragma unroll
        for (int mi = 0; mi < 2; ++mi)
            a[mi] = *(const sh8*)(tab + (w * 32 + mi * 16 + ln) * 256 + kc + q * 8);
        #pragma unroll
        for (int ni = 0; ni < 4; ++ni)
            bf[ni] = *(const sh8*)(ldsB + (ni * 16 + ln) * 272 + kc + q * 8);
        #pragma unroll
        for (int mi = 0; mi < 2; ++mi)
            #pragma unroll
            for (int ni = 0; ni < 4; ++ni)
                acc[mi][ni] = __builtin_amdgcn_mfma_f32_16x16x32_bf16(
                    a[mi], bf[ni], acc[mi][ni], 0, 0, 0);
    }
    // write Z[b][r][s][o]
    long zB = (long)b * 2097152 + (long)s * 64;
    #pragma unroll
    for (int mi = 0; mi < 2; ++mi)
        #pragma unroll
        for (int ni = 0; ni < 4; ++ni)
            #pragma unroll
            for (int reg = 0; reg < 4; ++reg) {
                int r = w * 32 + mi * 16 + q * 4 + reg;
                Zo[zB + (long)r * 16384 + ni * 16 + ln] = f2bf(acc[mi][ni][reg]);
            }
}

// ------------------------- MFMA complex mode-mix, both branches --------------
// Z layout [b][r][s][o]: freq rows 2m (Re) / 2m+1 (Im) are 16384-sh planes;
// lane stride along s is 64 sh (128 B) -> fully-coalesced reads and writes.
__global__ __launch_bounds__(256) void k_mixm2(
    unsigned short* Zy, unsigned short* Zx,
    const unsigned short* __restrict__ WrTy, const unsigned short* __restrict__ WiTy,
    const unsigned short* __restrict__ WinTy,
    const unsigned short* __restrict__ WrTx, const unsigned short* __restrict__ WiTx,
    const unsigned short* __restrict__ WinTx)
{
    int xt = blockIdx.x, g = blockIdx.y, z = blockIdx.z;
    unsigned short* Z = z ? Zx : Zy;
    const unsigned short* WrT  = z ? WrTx  : WrTy;
    const unsigned short* WiT  = z ? WiTx  : WiTy;
    const unsigned short* WinT = z ? WinTx : WinTy;
    int b = g >> 6, m = g & 63;
    int tid = threadIdx.x, w = tid >> 6, lane = tid & 63, q = lane >> 4, ln = lane & 15;
    long zBr = (long)b * 2097152 + (long)(2 * m) * 16384;   // Re plane; Im at +16384
    long wB = (long)b * 262144 + (long)m * 4096;
    int s0 = xt * 64 + w * 16;
    f4 aR[4], aI[4];
    #pragma unroll
    for (int nt = 0; nt < 4; ++nt) { aR[nt] = (f4){0.f,0.f,0.f,0.f}; aI[nt] = (f4){0.f,0.f,0.f,0.f}; }
    for (int kc = 0; kc < 64; kc += 32) {
        sh8 zr = *(const sh8*)(Z + zBr + (long)(s0 + ln) * 64 + kc + q * 8);
        sh8 zi = *(const sh8*)(Z + zBr + 16384 + (long)(s0 + ln) * 64 + kc + q * 8);
        #pragma unroll
        for (int nt = 0; nt < 4; ++nt) {
            int o = nt * 16 + ln;
            sh8 wr = *(const sh8*)(WrT + wB + o * 64 + kc + q * 8);
            sh8 wi = *(const sh8*)(WiT + wB + o * 64 + kc + q * 8);
            sh8 wn = *(const sh8*)(WinT + wB + o * 64 + kc + q * 8);
            aR[nt] = __builtin_amdgcn_mfma_f32_16x16x32_bf16(zr, wr, aR[nt], 0, 0, 0);
            aR[nt] = __builtin_amdgcn_mfma_f32_16x16x32_bf16(zi, wn, aR[nt], 0, 0, 0);
            aI[nt] = __builtin_amdgcn_mfma_f32_16x16x32_bf16(zr, wi, aI[nt], 0, 0, 0);
            aI[nt] = __builtin_amdgcn_mfma_f32_16x16x32_bf16(zi, wr, aI[nt], 0, 0, 0);
        }
    }
    #pragma unroll
    for (int nt = 0; nt < 4; ++nt)
        #pragma unroll
        for (int reg = 0; reg < 4; ++reg) {
            int s = s0 + q * 4 + reg;
            long a = zBr + (long)s * 64 + nt * 16 + ln;
            Z[a]          = f2bf(aR[nt][reg]);
            Z[a + 16384]  = f2bf(aI[nt][reg]);
        }
}

// ------------------------- MFMA inverse transform, both branches -------------
// Z layout [b][r][s][o]: stage with rowStride 16384 at base +s*64.
// BOTH branches write R in [b][x][y][o] layout:
//   z=0 (Ry): s = x, rows r2 = y -> addr = b*4M + s*16384 + r2*64 + o
//   z=1 (Rx): s = y, rows r2 = x -> addr = b*4M + r2*16384 + s*64 + o
__global__ __launch_bounds__(256) void k_ti2(
    const unsigned short* __restrict__ tabY, const unsigned short* __restrict__ tabX,
    const unsigned short* __restrict__ Zy, const unsigned short* __restrict__ Zx,
    unsigned short* __restrict__ Ry, unsigned short* __restrict__ Rx)
{
    __shared__ __align__(16) unsigned short ldsB[64 * 144];
    int g = blockIdx.x, br = blockIdx.y;
    int b = g >> 8, s = g & 255;
    const unsigned short* tab = br ? tabX : tabY;
    const unsigned short* Zl  = br ? Zx : Zy;
    unsigned short* Ro = br ? Rx : Ry;
    int tid = threadIdx.x;
    const unsigned short* src = Zl + (long)b * 2097152 + (long)s * 64;
    stage_bt(ldsB, 144, src, 16384, 128, tid);
    __syncthreads();
    int w = tid >> 6, lane = tid & 63, q = lane >> 4, ln = lane & 15;
    f4 acc[4][4];
    #pragma unroll
    for (int mi = 0; mi < 4; ++mi)
        #pragma unroll
        for (int ni = 0; ni < 4; ++ni) acc[mi][ni] = (f4){0.f, 0.f, 0.f, 0.f};
    for (int kc = 0; kc < 128; kc += 32) {
        sh8 a[4], bf[4];
        #pragma unroll
        for (int mi = 0; mi < 4; ++mi)
            a[mi] = *(const sh8*)(tab + (w * 64 + mi * 16 + ln) * 128 + kc + q * 8);
        #pragma unroll
        for (int ni = 0; ni < 4; ++ni)
            bf[ni] = *(const sh8*)(ldsB + (ni * 16 + ln) * 144 + kc + q * 8);
        #pragma unroll
        for (int mi = 0; mi < 4; ++mi)
            #pragma unroll
            for (int ni = 0; ni < 4; ++ni)
                acc[mi][ni] = __builtin_amdgcn_mfma_f32_16x16x32_bf16(
                    a[mi], bf[ni], acc[mi][ni], 0, 0, 0);
    }
    long rB0 = (long)b * 4194304;
    #pragma unroll
    for (int mi = 0; mi < 4; ++mi)
        #pragma unroll
        for (int ni = 0; ni < 4; ++ni)
            #pragma unroll
            for (int reg = 0; reg < 4; ++reg) {
                int r2 = w * 64 + mi * 16 + q * 4 + reg;
                long a;
                if (br) a = rB0 + (long)r2 * 16384 + (long)s * 64 + ni * 16 + ln;
                else    a = rB0 + (long)s * 16384 + (long)r2 * 64 + ni * 16 + ln;
                Ro[a] = f2bf(acc[mi][ni][reg]);
            }
}

// ------------------------- MFMA fused FeedForward + LN -----------------------
// A = bf16(Ry + Rx) built in registers; residual stream in bf16 (Hb).
// 1024 blocks x 4 row-tiles with register prefetch of next tile's Ry/Rx.
__global__ __launch_bounds__(256) void k_ffm(
    const unsigned short* __restrict__ Ry, const unsigned short* __restrict__ Rx,
    const unsigned short* __restrict__ W0T, const float* __restrict__ b0,
    const unsigned short* __restrict__ W1T, const float* __restrict__ b1,
    const float* __restrict__ g1, const float* __restrict__ be1,
    unsigned short* __restrict__ Hb, int last)
{
    __shared__ __align__(16) unsigned short T[64 * 264];
    int tid = threadIdx.x, w = tid >> 6, lane = tid & 63, q = lane >> 4, ln = lane & 15;
    int base0 = blockIdx.x * 256;        // 4 tiles of 64 rows
    // preload tile 0
    sh8 ryc[2], rxc[2];
    {
        long r0 = (long)(base0 + w * 16 + ln) * 64;
        ryc[0] = *(const sh8*)(Ry + r0 + q * 8);
        ryc[1] = *(const sh8*)(Ry + r0 + 32 + q * 8);
        rxc[0] = *(const sh8*)(Rx + r0 + q * 8);
        rxc[1] = *(const sh8*)(Rx + r0 + 32 + q * 8);
    }
    for (int it = 0; it < 4; ++it) {
        int m0 = base0 + it * 64;
        // prefetch tile it+1 (stays in flight across this tile's compute)
        sh8 ryn[2], rxn[2];
        if (it < 3) {
            long rn = (long)(m0 + 64 + w * 16 + ln) * 64;
            ryn[0] = *(const sh8*)(Ry + rn + q * 8);
            ryn[1] = *(const sh8*)(Ry + rn + 32 + q * 8);
            rxn[0] = *(const sh8*)(Rx + rn + q * 8);
            rxn[1] = *(const sh8*)(Rx + rn + 32 + q * 8);
        }
        // phase 1: T = relu((Ry+Rx) @ W0 + b0), wave rows w*16..+15, N=256
        {
            f4 acc1[16];
            #pragma unroll
            for (int nt = 0; nt < 16; ++nt) acc1[nt] = (f4){0.f, 0.f, 0.f, 0.f};
            #pragma unroll
            for (int kc2 = 0; kc2 < 2; ++kc2) {
                sh8 a;
                #pragma unroll
                for (int j = 0; j < 8; ++j)
                    a[j] = (short)f2bf(bf2f((unsigned short)ryc[kc2][j])
                                     + bf2f((unsigned short)rxc[kc2][j]));
                #pragma unroll
                for (int nt = 0; nt < 16; ++nt) {
                    sh8 bf = *(const sh8*)(W0T + (nt * 16 + ln) * 64 + kc2 * 32 + q * 8);
                    acc1[nt] = __builtin_amdgcn_mfma_f32_16x16x32_bf16(a, bf, acc1[nt], 0, 0, 0);
                }
            }
            #pragma unroll
            for (int nt = 0; nt < 16; ++nt) {
                int n = nt * 16 + ln;
                float bias = b0[n];
                #pragma unroll
                for (int reg = 0; reg < 4; ++reg) {
                    int m = w * 16 + q * 4 + reg;
                    T[m * 264 + n] = f2bf(fmaxf(acc1[nt][reg] + bias, 0.0f));
                }
            }
        }
        // residual loads for this tile (covered by phase 2's MFMA chain)
        float hbold[16];
        if (!last) {
            #pragma unroll
            for (int reg = 0; reg < 4; ++reg)
                #pragma unroll
                for (int nt = 0; nt < 4; ++nt)
                    hbold[reg * 4 + nt] =
                        bf2f(Hb[(long)(m0 + w * 16 + q * 4 + reg) * 64 + nt * 16 + ln]);
        }
        // phase 2 (intra-wave LDS dep): t = T @ W1 + b1, then LN + residual
        f4 acc2[4];
        #pragma unroll
        for (int nt = 0; nt < 4; ++nt) acc2[nt] = (f4){0.f, 0.f, 0.f, 0.f};
        for (int kc = 0; kc < 256; kc += 32) {
            sh8 a = *(const sh8*)(T + (w * 16 + ln) * 264 + kc + q * 8);
            #pragma unroll
            for (int nt = 0; nt < 4; ++nt) {
                sh8 bf = *(const sh8*)(W1T + (nt * 16 + ln) * 256 + kc + q * 8);
                acc2[nt] = __builtin_amdgcn_mfma_f32_16x16x32_bf16(a, bf, acc2[nt], 0, 0, 0);
            }
        }
        float bia[4], gg[4], bb4[4];
        #pragma unroll
        for (int nt = 0; nt < 4; ++nt) {
            int n = nt * 16 + ln;
            bia[nt] = b1[n]; gg[nt] = g1[n]; bb4[nt] = be1[n];
        }
        #pragma unroll
        for (int reg = 0; reg < 4; ++reg) {
            float t[4];
            float s = 0.f, qs = 0.f;
            #pragma unroll
            for (int nt = 0; nt < 4; ++nt) {
                t[nt] = acc2[nt][reg] + bia[nt];
                s += t[nt]; qs += t[nt] * t[nt];
            }
            #pragma unroll
            for (int d = 1; d < 16; d <<= 1) {
                s  += __shfl_xor(s, d, 64);
                qs += __shfl_xor(qs, d, 64);
            }
            float mean = s * (1.0f / 64.0f);
            float var  = qs * (1.0f / 64.0f) - mean * mean;
            float inv  = rsqrtf(var + 1e-5f);
            int m = w * 16 + q * 4 + reg;
            long base = (long)(m0 + m) * 64;
            #pragma unroll
            for (int nt = 0; nt < 4; ++nt) {
                int n = nt * 16 + ln;
                float v = (t[nt] - mean) * inv * gg[nt] + bb4[nt];
                float hv;
                if (last) hv = gelu_fast(v);
                else      hv = hbold[reg * 4 + nt] + v;
                Hb[base + n] = f2bf(hv);
            }
        }
        // rotate prefetched tile into current (only when a prefetch happened)
        if (it < 3) {
            ryc[0] = ryn[0]; ryc[1] = ryn[1];
            rxc[0] = rxn[0]; rxc[1] = rxn[1];
        }
    }
}

// ------------------------- output heads (MFMA ha + fp32 conv) ----------------
// px-quarter per dispatch (pxQ): dim3(256,5) x 4 launches. Same math as R4.
__global__ __launch_bounds__(256) void k_headm(
    const unsigned short* __restrict__ Hb, const float* __restrict__ x0,
    const unsigned short* __restrict__ Wcat, const float* __restrict__ bcat,
    const float* __restrict__ c1w, const float* __restrict__ c1b,
    const float* __restrict__ c2w, const float* __restrict__ c2b,
    float* __restrict__ out, int pxQ)
{
    __shared__ unsigned short ha[256 * 74];   // [px][j], pitch 74 (gcd(37,32)=1)
    int tid = threadIdx.x;
    int f = blockIdx.y;
    long px0 = (long)(pxQ * 256 + blockIdx.x) * 256;
    int w = tid >> 6, lane = tid & 63, q = lane >> 4, ln = lane & 15;

    // ha-GEMM, one mi (16 rows) at a time: acc[5] live, not acc[4][5]
    #pragma unroll
    for (int mi = 0; mi < 4; ++mi) {
        f4 acc[5];
        #pragma unroll
        for (int nt = 0; nt < 5; ++nt) acc[nt] = (f4){0.f, 0.f, 0.f, 0.f};
        #pragma unroll
        for (int kc = 0; kc < 2; ++kc) {
            sh8 a = *(const sh8*)(Hb + (px0 + w * 64 + mi * 16 + ln) * 64
                                   + kc * 32 + q * 8);
            #pragma unroll
            for (int nt = 0; nt < 5; ++nt) {
                sh8 bf = *(const sh8*)(Wcat + f * 5120 + (nt * 16 + ln) * 64
                                        + kc * 32 + q * 8);
                acc[nt] = __builtin_amdgcn_mfma_f32_16x16x32_bf16(a, bf, acc[nt], 0, 0, 0);
            }
        }
        #pragma unroll
        for (int nt = 0; nt < 5; ++nt) {
            int n = nt * 16 + ln;
            if (n < 70) {
                float bias = bcat[f * 80 + n];
                #pragma unroll
                for (int reg = 0; reg < 4; ++reg) {
                    int m = w * 64 + mi * 16 + q * 4 + reg;
                    ha[m * 74 + n] = f2bf(gelu_fast(acc[nt][reg] + bias));
                }
            }
        }
    }
    __syncthreads();

    // conv phase: one pixel per thread, fp32 FMA.
    float u2[10];
    float b2v = c2b[f];
    #pragma unroll
    for (int d = 0; d < 10; ++d) u2[d] = b2v;
    #pragma unroll
    for (int h = 0; h < 2; ++h) {
        float hw[40];   // hv[30h .. 30h+39]
        #pragma unroll
        for (int i = 0; i < 20; ++i) {
            unsigned int u = *(const unsigned int*)(ha + tid * 74 + h * 30 + 2 * i);
            hw[2 * i]     = __uint_as_float(u << 16);
            hw[2 * i + 1] = __uint_as_float(u & 0xffff0000u);
        }
        #pragma unroll 1
        for (int c = 0; c < 8; ++c) {
            int fc = f * 8 + c;
            float w1r[12], w2r[12];   // wave-uniform -> SGPRs
            #pragma unroll
            for (int j = 0; j < 12; ++j) {
                w1r[j] = c1w[fc * 12 + j];
                w2r[j] = c2w[fc * 12 + j];
            }
            float bc = c1b[fc];
            #pragma unroll
            for (int pl = 0; pl < 15; ++pl) {
                const int p = h * 15 + pl;     // compile-time after unroll
                float s = bc;
                #pragma unroll
                for (int j = 0; j < 12; ++j)
                    s = fmaf(hw[2 * pl + j], w1r[j], s);
                float g = gelu_fast(s);
                #pragma unroll
                for (int d = 0; d < 10; ++d) {
                    const int j2 = p - 2 * d;  // compile-time bounds
                    if (j2 >= 0 && j2 < 12)
                        u2[d] = fmaf(g, w2r[j2], u2[d]);
                }
            }
        }
    }
    long px = px0 + tid;
    float xv = x0[px * 5 + f];
    #pragma unroll
    for (int d = 0; d < 10; ++d)
        out[px * 50 + f * 10 + d] = xv + u2[d] * (float)(d + 1) * 0.1f;
}

// ---------------------------------------------------------------------------
extern "C" void kernel_launch(void* const* d_in, const int* in_sizes, int n_in,
                              void* d_out, int out_size, void* d_ws, size_t ws_size,
                              hipStream_t stream) {
    (void)in_sizes; (void)n_in; (void)out_size; (void)ws_size;
    const float* xin    = (const float*)d_in[0];
    const float* params = (const float*)d_in[1];
    const float* in_w   = (const float*)d_in[2];
    const float* in_b   = (const float*)d_in[3];
    const float* fnu_w1 = (const float*)d_in[4];
    const float* fnu_b1 = (const float*)d_in[5];
    const float* fnu_w2 = (const float*)d_in[6];
    const float* fnu_b2 = (const float*)d_in[7];
    const float* fnu_w3 = (const float*)d_in[8];
    const float* fnu_b3 = (const float*)d_in[9];
    const float* fw_y   = (const float*)d_in[10];
    const float* fw_x   = (const float*)d_in[11];
    const float* ff_w0  = (const float*)d_in[12];
    const float* ff_b0  = (const float*)d_in[13];
    const float* ff_w1  = (const float*)d_in[14];
    const float* ff_b1  = (const float*)d_in[15];
    const float* ln_g   = (const float*)d_in[16];
    const float* ln_b   = (const float*)d_in[17];
    const float* fa_w   = (const float*)d_in[18];
    const float* fa_b   = (const float*)d_in[19];
    const float* fb_w   = (const float*)d_in[20];
    const float* fb_b   = (const float*)d_in[21];
    const float* c1_w   = (const float*)d_in[22];
    const float* c1_b   = (const float*)d_in[23];
    const float* c2_w   = (const float*)d_in[24];
    const float* c2_b   = (const float*)d_in[25];
    float* out = (float*)d_out;
    float* ws  = (float*)d_ws;

    // workspace (float offsets), total ~41.0M floats (~164 MB)
    unsigned short* tabBf = (unsigned short*)(ws + 0);        // 131072 sh
    unsigned short* tabYF = tabBf;
    unsigned short* tabXF = tabBf + 32768;
    unsigned short* tabYI = tabBf + 65536;
    unsigned short* tabXI = tabBf + 98304;
    unsigned short* W0T   = (unsigned short*)(ws + 65536);    // 65536 sh
    unsigned short* W1T   = (unsigned short*)(ws + 98304);    // 65536 sh
    unsigned short* Wcat  = (unsigned short*)(ws + 131072);   // 25600 sh
    float* bcat = ws + 143872;                                 // 400
    float* att  = ws + 144272;                                 // 64
    unsigned int* c1p = (unsigned int*)(ws + 144336);          // 240 (layout compat)
    unsigned int* c2p = (unsigned int*)(ws + 144576);          // 240 (layout compat)
    unsigned short* Hbf = (unsigned short*)(ws + 144816);      // 16.8M sh
    // WRy..WIx fp32 slots (ws+8533424..) unused since R5 (wfuse writes bf16 direct)
    unsigned short* WrTy  = (unsigned short*)(ws + 12727728);  // 1M sh each
    unsigned short* WiTy  = (unsigned short*)(ws + 13252016);
    unsigned short* WinTy = (unsigned short*)(ws + 13776304);
    unsigned short* WrTx  = (unsigned short*)(ws + 14300592);
    unsigned short* WiTx  = (unsigned short*)(ws + 14824880);
    unsigned short* WinTx = (unsigned short*)(ws + 15349168);
    unsigned short* Zy    = (unsigned short*)(ws + 15873456);  // 8.4M sh
    unsigned short* Zx    = (unsigned short*)(ws + 20067760);  // 8.4M sh
    unsigned short* Ry    = (unsigned short*)(ws + 24262064);  // 16.8M sh
    unsigned short* Rx    = (unsigned short*)(ws + 32650672);  // 16.8M sh

    // fused front: att (16 parallel blocks) + prep + embed in one dispatch
    k_front<<<17528, 256, 0, stream>>>(
        ff_w0, ff_w1, fa_w, fb_w, fa_b, fb_b, c1_w, c2_w,
        tabBf, W0T, W1T, Wcat, bcat, c1p, c2p,
        params, fnu_w1, fnu_b1, fnu_w2, fnu_b2, fnu_w3, fnu_b3, att,
        xin, in_w, in_b, Hbf);

    for (int lay = 0; lay < 4; ++lay) {
        const float* attL = att + lay * 16;
        // fused W-gen + forward transform (independent halves)
        k_wtf<<<2560, 256, 0, stream>>>(
            fw_y + (long)lay * 2097152, fw_x + (long)lay * 2097152, attL,
            WrTy, WiTy, WinTy, WrTx, WiTx, WinTx,
            tabYF, tabXF, Hbf, Zy, Zx);
        k_mixm2<<<dim3(4, 256, 2), 256, 0, stream>>>(
            Zy, Zx, WrTy, WiTy, WinTy, WrTx, WiTx, WinTx);
        k_ti2<<<dim3(1024, 2), 256, 0, stream>>>(tabYI, tabXI, Zy, Zx, Ry, Rx);
        k_ffm<<<1024, 256, 0, stream>>>(
            Ry, Rx, W0T + lay * 16384, ff_b0 + lay * 256,
            W1T + lay * 16384, ff_b1 + lay * 64,
            ln_g + lay * 64, ln_b + lay * 64,
            Hbf, (lay == 3) ? 1 : 0);
    }
    // k_headm split into 4 px-quarters (~65us each): keeps layer kernels
    // visible in the top-5 dispatch table with full counters.
    for (int pq = 0; pq < 4; ++pq)
        k_headm<<<dim3(256, 5), 256, 0, stream>>>(Hbf, xin, Wcat, bcat,
                                                  c1_w, c1_b, c2_w, c2_b, out, pq);
}